// Round 5
// baseline (11010.697 us; speedup 1.0000x reference)
//
#include <hip/hip_runtime.h>

// Problem: B=2, S=2048, Dm=1024, H=16, D=64, MAX_REL=2.
// All-fp32 scalar pipeline (correctness-first; MFMA reintroduced later).
#define S_LEN 2048
#define DM    1024
#define NH    16
#define HD    64
#define BATCH 2

typedef __attribute__((ext_vector_type(4))) float f4;

// ---------------------------------------------------------------------------
// QKV slice projection for (batch b, head-group hg): tiled scalar GEMM.
// grid (32, 12): blockIdx.y>>2 = matrix (0=Q,1=K,2=V); &3 = 64-col tile.
// Writes Qs/Ks [hh][s][d], Vts [hh][d][s] (fp32), hh = local head 0..3.
// ---------------------------------------------------------------------------
__global__ __launch_bounds__(256) void proj_slice(
    const float* __restrict__ x,    // [B][S][DM]
    const float* __restrict__ Wq,
    const float* __restrict__ Wk,
    const float* __restrict__ Wv,
    const float* __restrict__ bq,
    const float* __restrict__ bk,
    const float* __restrict__ bv,
    float* __restrict__ Qs,         // [4][S][HD]
    float* __restrict__ Ks,         // [4][S][HD]
    float* __restrict__ Vts,        // [4][HD][S]
    int b, int hg)
{
    __shared__ float As[64][17];
    __shared__ float Bs[16][65];

    int tid = threadIdx.x;
    int tx = tid & 15, ty = tid >> 4;
    int m0 = blockIdx.x * 64;
    int mat = blockIdx.y >> 2;
    int n0l = (blockIdx.y & 3) * 64;          // local col tile base in [0,256)
    int gc0 = hg * 256 + n0l;                 // global col base

    const float* W    = (mat == 0) ? Wq : (mat == 1) ? Wk : Wv;
    const float* bias = (mat == 0) ? bq : (mat == 1) ? bk : bv;
    const float* xb = x + (size_t)b * S_LEN * DM;

    float c[4][4];
#pragma unroll
    for (int i = 0; i < 4; i++)
#pragma unroll
        for (int j = 0; j < 4; j++) c[i][j] = 0.f;

    int ar = tid >> 2, ac = (tid & 3) * 4;    // A-tile loader coords
    for (int k0 = 0; k0 < DM; k0 += 16) {
#pragma unroll
        for (int j = 0; j < 4; j++)
            As[ar][ac + j] = xb[(size_t)(m0 + ar) * DM + k0 + ac + j];
#pragma unroll
        for (int j = 0; j < 4; j++)
            Bs[ty][tx * 4 + j] = W[(size_t)(k0 + ty) * DM + gc0 + tx * 4 + j];
        __syncthreads();
#pragma unroll
        for (int k = 0; k < 16; k++) {
            float a0 = As[ty * 4 + 0][k], a1 = As[ty * 4 + 1][k];
            float a2 = As[ty * 4 + 2][k], a3 = As[ty * 4 + 3][k];
            float b0 = Bs[k][tx * 4 + 0], b1 = Bs[k][tx * 4 + 1];
            float b2 = Bs[k][tx * 4 + 2], b3 = Bs[k][tx * 4 + 3];
            c[0][0] += a0 * b0; c[0][1] += a0 * b1; c[0][2] += a0 * b2; c[0][3] += a0 * b3;
            c[1][0] += a1 * b0; c[1][1] += a1 * b1; c[1][2] += a1 * b2; c[1][3] += a1 * b3;
            c[2][0] += a2 * b0; c[2][1] += a2 * b1; c[2][2] += a2 * b2; c[2][3] += a2 * b3;
            c[3][0] += a3 * b0; c[3][1] += a3 * b1; c[3][2] += a3 * b2; c[3][3] += a3 * b3;
        }
        __syncthreads();
    }

#pragma unroll
    for (int i = 0; i < 4; i++) {
        int m = m0 + ty * 4 + i;              // sequence position s
#pragma unroll
        for (int j = 0; j < 4; j++) {
            int nl = n0l + tx * 4 + j;        // local col in [0,256)
            float v = c[i][j] + bias[hg * 256 + nl];
            int hh = nl >> 6, d = nl & 63;
            if (mat == 2)
                Vts[((size_t)hh * HD + d) * S_LEN + m] = v;
            else if (mat == 0)
                Qs[((size_t)hh * S_LEN + m) * HD + d] = v;
            else
                Ks[((size_t)hh * S_LEN + m) * HD + d] = v;
        }
    }
}

// ---------------------------------------------------------------------------
// Scalar fused relative attention: one block = (head hh, 16-row q-tile).
// fp32 2048-wide score rows in LDS; scalar dot scores; softmax + bucket
// sums (16 threads/row); scalar PV; rel_v bucket epilogue.
// ---------------------------------------------------------------------------
__global__ __launch_bounds__(256) void attn_scalar(
    const float* __restrict__ Qs,    // [4][S][HD]
    const float* __restrict__ Ks,    // [4][S][HD]
    const float* __restrict__ Vts,   // [4][HD][S]
    const float* __restrict__ relk,  // [5][64]
    const float* __restrict__ relv,  // [5][64]
    float* __restrict__ AO,          // [S][DM] per-batch
    int col_base)                    // hg*256
{
    __shared__ float sc[16][S_LEN];  // 128 KB
    __shared__ float qs[16][HD];     // 4 KB
    __shared__ float qr[16][5];
    __shared__ float rowstat[16][8];

    int tid = threadIdx.x;
    int q0 = blockIdx.x * 16;
    int hh = blockIdx.y;

    const float* Qh = Qs + (size_t)hh * S_LEN * HD;
    const float* Kh = Ks + (size_t)hh * S_LEN * HD;
    const float* Vh = Vts + (size_t)hh * HD * S_LEN;

    // stage the 16 q-rows
    for (int i = tid; i < 16 * HD; i += 256)
        qs[i >> 6][i & 63] = Qh[(size_t)(q0 + (i >> 6)) * HD + (i & 63)];
    __syncthreads();

    // q . rel_k[j]
    if (tid < 80) {
        int row = tid / 5, j = tid % 5;
        float s = 0.f;
        for (int d = 0; d < HD; d++) s += qs[row][d] * relk[j * HD + d];
        qr[row][j] = s;
    }

    // ---- scores: thread t owns k-columns {t, t+256, ...} ----
    for (int kk = 0; kk < 8; kk++) {
        int k = kk * 256 + tid;
        const f4* kp = (const f4*)(Kh + (size_t)k * HD);
        float s[16];
#pragma unroll
        for (int row = 0; row < 16; row++) s[row] = 0.f;
#pragma unroll
        for (int d4 = 0; d4 < 16; d4++) {
            f4 kv = kp[d4];
#pragma unroll
            for (int row = 0; row < 16; row++) {
                f4 qv = *(const f4*)&qs[row][d4 * 4];
                s[row] += qv[0] * kv[0] + qv[1] * kv[1] + qv[2] * kv[2] + qv[3] * kv[3];
            }
        }
#pragma unroll
        for (int row = 0; row < 16; row++) sc[row][k] = s[row];
    }
    __syncthreads();

    // ---- softmax + bucket sums: 16 threads per row ----
    {
        int row = tid >> 4, c0 = tid & 15;
        int qglob = q0 + row;
        float mx = -1e30f;
        for (int c = c0; c < S_LEN; c += 16) {
            int del = min(2, max(-2, c - qglob));
            float s = (sc[row][c] + qr[row][del + 2]) * 0.125f;   // /sqrt(64)
            sc[row][c] = s;
            mx = fmaxf(mx, s);
        }
#pragma unroll
        for (int off = 8; off > 0; off >>= 1) mx = fmaxf(mx, __shfl_xor(mx, off, 16));

        float denom = 0.f, suf = 0.f;
        for (int c = c0; c < S_LEN; c += 16) {
            float e = __expf(fminf(sc[row][c] - mx, 0.f));
            sc[row][c] = e;
            denom += e;
            if (c >= qglob + 2) suf += e;
        }
#pragma unroll
        for (int off = 8; off > 0; off >>= 1) {
            denom += __shfl_xor(denom, off, 16);
            suf   += __shfl_xor(suf,   off, 16);
        }
        if (c0 == 0) {
            float b1  = (qglob >= 1) ? sc[row][qglob - 1] : 0.f;
            float b2v = sc[row][qglob];
            float b3  = (qglob + 1 < S_LEN) ? sc[row][qglob + 1] : 0.f;
            float b0  = denom - suf - b1 - b2v - b3;   // prefix k <= q-2
            rowstat[row][0] = 1.f / denom;
            rowstat[row][1] = b0;
            rowstat[row][2] = b1;
            rowstat[row][3] = b2v;
            rowstat[row][4] = b3;
            rowstat[row][5] = suf;
        }
    }
    __syncthreads();

    // ---- PV + rel_v epilogue: thread t owns 4 (row,d) pairs ----
    for (int pi = 0; pi < 4; pi++) {
        int idx = pi * 256 + tid;
        int row = idx >> 6, d = idx & 63;
        const f4* vp = (const f4*)(Vh + (size_t)d * S_LEN);
        const f4* pp = (const f4*)&sc[row][0];
        float o = 0.f;
        for (int k4 = 0; k4 < S_LEN / 4; k4++) {
            f4 p = pp[k4], v = vp[k4];
            o += p[0] * v[0] + p[1] * v[1] + p[2] * v[2] + p[3] * v[3];
        }
        float o2 = rowstat[row][1] * relv[0 * HD + d]
                 + rowstat[row][2] * relv[1 * HD + d]
                 + rowstat[row][3] * relv[2 * HD + d]
                 + rowstat[row][4] * relv[3 * HD + d]
                 + rowstat[row][5] * relv[4 * HD + d];
        AO[(size_t)(q0 + row) * DM + col_base + hh * HD + d] = (o + o2) * rowstat[row][0];
    }
}

// ---------------------------------------------------------------------------
// out[b] = AO @ Wo + bo  (tiled scalar GEMM, fp32 out). grid (32, 16).
// ---------------------------------------------------------------------------
__global__ __launch_bounds__(256) void outproj_scalar(
    const float* __restrict__ AO,    // [S][DM]
    const float* __restrict__ Wo,    // [DM][DM]
    const float* __restrict__ bo,
    float* __restrict__ out,         // [B][S][DM]
    int b)
{
    __shared__ float As[64][17];
    __shared__ float Bs[16][65];

    int tid = threadIdx.x;
    int tx = tid & 15, ty = tid >> 4;
    int m0 = blockIdx.x * 64;
    int n0 = blockIdx.y * 64;

    float c[4][4];
#pragma unroll
    for (int i = 0; i < 4; i++)
#pragma unroll
        for (int j = 0; j < 4; j++) c[i][j] = 0.f;

    int ar = tid >> 2, ac = (tid & 3) * 4;
    for (int k0 = 0; k0 < DM; k0 += 16) {
#pragma unroll
        for (int j = 0; j < 4; j++)
            As[ar][ac + j] = AO[(size_t)(m0 + ar) * DM + k0 + ac + j];
#pragma unroll
        for (int j = 0; j < 4; j++)
            Bs[ty][tx * 4 + j] = Wo[(size_t)(k0 + ty) * DM + n0 + tx * 4 + j];
        __syncthreads();
#pragma unroll
        for (int k = 0; k < 16; k++) {
            float a0 = As[ty * 4 + 0][k], a1 = As[ty * 4 + 1][k];
            float a2 = As[ty * 4 + 2][k], a3 = As[ty * 4 + 3][k];
            float b0 = Bs[k][tx * 4 + 0], b1 = Bs[k][tx * 4 + 1];
            float b2 = Bs[k][tx * 4 + 2], b3 = Bs[k][tx * 4 + 3];
            c[0][0] += a0 * b0; c[0][1] += a0 * b1; c[0][2] += a0 * b2; c[0][3] += a0 * b3;
            c[1][0] += a1 * b0; c[1][1] += a1 * b1; c[1][2] += a1 * b2; c[1][3] += a1 * b3;
            c[2][0] += a2 * b0; c[2][1] += a2 * b1; c[2][2] += a2 * b2; c[2][3] += a2 * b3;
            c[3][0] += a3 * b0; c[3][1] += a3 * b1; c[3][2] += a3 * b2; c[3][3] += a3 * b3;
        }
        __syncthreads();
    }

#pragma unroll
    for (int i = 0; i < 4; i++) {
        int m = m0 + ty * 4 + i;
#pragma unroll
        for (int j = 0; j < 4; j++) {
            int n = n0 + tx * 4 + j;
            out[((size_t)b * S_LEN + m) * DM + n] = c[i][j] + bo[n];
        }
    }
}

// ---------------------------------------------------------------------------
// Workspace (fp32): Qs/Ks/Vts 524288 floats each (2 MB), AOb 2M floats (8 MB).
// Total 14 MB. Loop b: { loop hg: proj -> attn } -> outproj(b). Stream-ordered.
// ---------------------------------------------------------------------------
extern "C" void kernel_launch(void* const* d_in, const int* in_sizes, int n_in,
                              void* d_out, int out_size, void* d_ws, size_t ws_size,
                              hipStream_t stream)
{
    const float* x  = (const float*)d_in[0];
    const float* Wq = (const float*)d_in[1];
    const float* bq = (const float*)d_in[2];
    const float* Wk = (const float*)d_in[3];
    const float* bk = (const float*)d_in[4];
    const float* Wv = (const float*)d_in[5];
    const float* bv = (const float*)d_in[6];
    const float* Wo = (const float*)d_in[7];
    const float* bo = (const float*)d_in[8];
    const float* rk = (const float*)d_in[9];
    const float* rv = (const float*)d_in[10];
    float* outp = (float*)d_out;

    float* ws  = (float*)d_ws;
    float* Qs  = ws;                 // 524288
    float* Ks  = ws + 524288;        // 524288
    float* Vts = ws + 1048576;       // 524288
    float* AOb = ws + 1572864;       // 2097152

    for (int b = 0; b < BATCH; b++) {
        for (int hg = 0; hg < 4; hg++) {
            proj_slice<<<dim3(32, 12), 256, 0, stream>>>(
                x, Wq, Wk, Wv, bq, bk, bv, Qs, Ks, Vts, b, hg);
            attn_scalar<<<dim3(S_LEN / 16, 4), 256, 0, stream>>>(
                Qs, Ks, Vts, rk, rv, AOb, hg * 256);
        }
        outproj_scalar<<<dim3(32, 16), 256, 0, stream>>>(AOb, Wo, bo, outp, b);
    }
}

// Round 7
// 3267.861 us; speedup vs baseline: 3.3694x; 3.3694x over previous
//
#include <hip/hip_runtime.h>

// Problem: B=2, S=2048, Dm=1024, H=16, D=64, MAX_REL=2. Inputs/out fp32.
// Round 7: DIAGNOSTIC attn — MFMA QK^T with in-kernel scalar self-check and
// scalar-recompute fallback; scalar PV (round-5 proven). proj/outproj proven.
#define S_LEN 2048
#define DM    1024
#define NH    16
#define HD    64
#define BATCH 2
#define SPAD  2056

typedef __attribute__((ext_vector_type(8))) short short8;
typedef __attribute__((ext_vector_type(4))) float f32x4;

__device__ inline float b2f(unsigned short u) {
    return __uint_as_float(((unsigned)u) << 16);
}
__device__ inline unsigned short f2b(float f) {
    unsigned u = __float_as_uint(f);
    u += 0x7FFFu + ((u >> 16) & 1u);   // RNE
    return (unsigned short)(u >> 16);
}
__device__ inline f32x4 zero4() {
    f32x4 z; z[0] = 0.f; z[1] = 0.f; z[2] = 0.f; z[3] = 0.f; return z;
}

// ---------------------------------------------------------------------------
// QKV slice projection (round-5 proven math; bf16 stores).
// ---------------------------------------------------------------------------
__global__ __launch_bounds__(256) void proj_slice(
    const float* __restrict__ x,
    const float* __restrict__ Wq,
    const float* __restrict__ Wk,
    const float* __restrict__ Wv,
    const float* __restrict__ bq,
    const float* __restrict__ bk,
    const float* __restrict__ bv,
    unsigned short* __restrict__ Qs,   // [4][S][HD] bf16
    unsigned short* __restrict__ Ks,   // [4][S][HD] bf16
    unsigned short* __restrict__ Vts,  // [4][HD][S] bf16
    int b, int hg)
{
    __shared__ float As[64][17];
    __shared__ float Bs[16][65];

    int tid = threadIdx.x;
    int tx = tid & 15, ty = tid >> 4;
    int m0 = blockIdx.x * 64;
    int mat = blockIdx.y >> 2;
    int n0l = (blockIdx.y & 3) * 64;
    int gc0 = hg * 256 + n0l;

    const float* W    = (mat == 0) ? Wq : (mat == 1) ? Wk : Wv;
    const float* bias = (mat == 0) ? bq : (mat == 1) ? bk : bv;
    const float* xb = x + (size_t)b * S_LEN * DM;

    float c[4][4];
#pragma unroll
    for (int i = 0; i < 4; i++)
#pragma unroll
        for (int j = 0; j < 4; j++) c[i][j] = 0.f;

    int ar = tid >> 2, ac = (tid & 3) * 4;
    for (int k0 = 0; k0 < DM; k0 += 16) {
#pragma unroll
        for (int j = 0; j < 4; j++)
            As[ar][ac + j] = xb[(size_t)(m0 + ar) * DM + k0 + ac + j];
#pragma unroll
        for (int j = 0; j < 4; j++)
            Bs[ty][tx * 4 + j] = W[(size_t)(k0 + ty) * DM + gc0 + tx * 4 + j];
        __syncthreads();
#pragma unroll
        for (int k = 0; k < 16; k++) {
            float a0 = As[ty * 4 + 0][k], a1 = As[ty * 4 + 1][k];
            float a2 = As[ty * 4 + 2][k], a3 = As[ty * 4 + 3][k];
            float b0 = Bs[k][tx * 4 + 0], b1 = Bs[k][tx * 4 + 1];
            float b2 = Bs[k][tx * 4 + 2], b3 = Bs[k][tx * 4 + 3];
            c[0][0] += a0 * b0; c[0][1] += a0 * b1; c[0][2] += a0 * b2; c[0][3] += a0 * b3;
            c[1][0] += a1 * b0; c[1][1] += a1 * b1; c[1][2] += a1 * b2; c[1][3] += a1 * b3;
            c[2][0] += a2 * b0; c[2][1] += a2 * b1; c[2][2] += a2 * b2; c[2][3] += a2 * b3;
            c[3][0] += a3 * b0; c[3][1] += a3 * b1; c[3][2] += a3 * b2; c[3][3] += a3 * b3;
        }
        __syncthreads();
    }

#pragma unroll
    for (int i = 0; i < 4; i++) {
        int m = m0 + ty * 4 + i;
#pragma unroll
        for (int j = 0; j < 4; j++) {
            int nl = n0l + tx * 4 + j;
            float v = c[i][j] + bias[hg * 256 + nl];
            int hh = nl >> 6, d = nl & 63;
            if (mat == 2)
                Vts[((size_t)hh * HD + d) * S_LEN + m] = f2b(v);
            else if (mat == 0)
                Qs[((size_t)hh * S_LEN + m) * HD + d] = f2b(v);
            else
                Ks[((size_t)hh * S_LEN + m) * HD + d] = f2b(v);
        }
    }
}

// ---------------------------------------------------------------------------
// Hybrid diagnostic attention: MFMA QK^T + self-check + scalar heal;
// scalar PV; proven softmax/buckets.
// ---------------------------------------------------------------------------
__global__ __launch_bounds__(256) void attn_hybrid(
    const unsigned short* __restrict__ Q,    // [4][S][HD] bf16
    const unsigned short* __restrict__ Km,   // [4][S][HD] bf16
    const unsigned short* __restrict__ Vt,   // [4][HD][S] bf16
    const float* __restrict__ relk,          // [5][64] fp32
    const float* __restrict__ relv,          // [5][64] fp32
    unsigned short* __restrict__ Aout,       // [S][DM] bf16 per-batch
    int col_base)
{
    __shared__ float sc[16][SPAD];           // 131.6 KB
    __shared__ float qs[16][HD];             // 4 KB fp32 q-tile
    __shared__ float qrel_s[16][5];
    __shared__ float relv_s[5][HD];
    __shared__ float rowstat[16][8];
    __shared__ int   badflag;

    int tid = threadIdx.x;
    int wave = tid >> 6, lane = tid & 63;
    int r = lane & 15, quad = lane >> 4;
    int q0 = blockIdx.x * 16;
    int hh = blockIdx.y;

    size_t qk_base = (size_t)hh * S_LEN * HD;
    size_t v_base  = (size_t)hh * HD * S_LEN;

    if (tid == 0) badflag = 0;
    for (int i = tid; i < 16 * HD; i += 256)
        qs[i >> 6][i & 63] = b2f(Q[qk_base + (size_t)(q0 + (i >> 6)) * HD + (i & 63)]);
    for (int i = tid; i < 5 * HD; i += 256)
        relv_s[i >> 6][i & 63] = relv[i];

    // A-fragments for QK^T (assumed A[m=lane&15][k=quad*8+j])
    const short8* qp8 = (const short8*)(Q + qk_base + (size_t)(q0 + r) * HD + quad * 8);
    short8 aq0 = qp8[0];
    short8 aq1 = qp8[4];

    __syncthreads();   // qs ready

    if (tid < 80) {
        int row = tid / 5, j = tid % 5;
        float s = 0.f;
        for (int d = 0; d < HD; d++) s += qs[row][d] * relk[j * HD + d];
        qrel_s[row][j] = s;
    }

    // ---- QK^T via MFMA: wave w covers cols [w*512, (w+1)*512) ----
    for (int t = 0; t < 32; t++) {
        int n0 = wave * 512 + t * 16;
        const short8* kp = (const short8*)(Km + qk_base + (size_t)(n0 + r) * HD + quad * 8);
        short8 bk0 = kp[0];
        short8 bk1 = kp[4];
        f32x4 a1 = zero4();
        a1 = __builtin_amdgcn_mfma_f32_16x16x32_bf16(aq0, bk0, a1, 0, 0, 0);
        a1 = __builtin_amdgcn_mfma_f32_16x16x32_bf16(aq1, bk1, a1, 0, 0, 0);
#pragma unroll
        for (int i = 0; i < 4; i++) sc[quad * 4 + i][n0 + r] = a1[i];
    }
    __syncthreads();

    // ---- self-check: 16 scalar reference scores, spread across waves,
    //      provably off the 16-block diagonal (2row+5 != 0 mod 16) ----
    if (tid < 16) {
        int row = tid;
        int col = (row * 131 + 37) & (S_LEN - 1);
        const unsigned short* kp = Km + qk_base + (size_t)col * HD;
        float sref = 0.f;
        for (int d = 0; d < HD; d++) sref += qs[row][d] * b2f(kp[d]);
        float got = sc[row][col];
        if (fabsf(sref - got) > 0.05f * (1.f + fabsf(sref))) badflag = 1;
    }
    __syncthreads();

    if (badflag) {
        // heal: recompute ALL scores scalarly (round-5-proven pattern)
        for (int kk = 0; kk < 8; kk++) {
            int k = kk * 256 + tid;
            const short8* kp8 = (const short8*)(Km + qk_base + (size_t)k * HD);
            float s[16];
#pragma unroll
            for (int row = 0; row < 16; row++) s[row] = 0.f;
            for (int d8 = 0; d8 < 8; d8++) {
                short8 kv = kp8[d8];
                float kf[8];
#pragma unroll
                for (int j = 0; j < 8; j++) kf[j] = b2f(kv[j]);
#pragma unroll
                for (int row = 0; row < 16; row++) {
#pragma unroll
                    for (int j = 0; j < 8; j++)
                        s[row] += qs[row][d8 * 8 + j] * kf[j];
                }
            }
#pragma unroll
            for (int row = 0; row < 16; row++) sc[row][k] = s[row];
        }
        __syncthreads();
    }

    // ---- softmax + bucket sums (round-5 proven) ----
    {
        int row = tid >> 4, c0 = tid & 15;
        int qglob = q0 + row;
        float mx = -1e30f;
        for (int c = c0; c < S_LEN; c += 16) {
            int del = min(2, max(-2, c - qglob));
            float s = (sc[row][c] + qrel_s[row][del + 2]) * 0.125f;
            sc[row][c] = s;
            mx = fmaxf(mx, s);
        }
#pragma unroll
        for (int off = 8; off > 0; off >>= 1) mx = fmaxf(mx, __shfl_xor(mx, off, 16));

        float denom = 0.f, suf = 0.f;
        for (int c = c0; c < S_LEN; c += 16) {
            float e = __expf(fminf(sc[row][c] - mx, 0.f));
            sc[row][c] = e;
            denom += e;
            if (c >= qglob + 2) suf += e;
        }
#pragma unroll
        for (int off = 8; off > 0; off >>= 1) {
            denom += __shfl_xor(denom, off, 16);
            suf   += __shfl_xor(suf,   off, 16);
        }
        if (c0 == 0) {
            float b1  = (qglob >= 1) ? sc[row][qglob - 1] : 0.f;
            float b2v = sc[row][qglob];
            float b3  = (qglob + 1 < S_LEN) ? sc[row][qglob + 1] : 0.f;
            float b0  = denom - suf - b1 - b2v - b3;
            rowstat[row][0] = 1.f / denom;
            rowstat[row][1] = b0;
            rowstat[row][2] = b1;
            rowstat[row][3] = b2v;
            rowstat[row][4] = b3;
            rowstat[row][5] = suf;
        }
    }
    __syncthreads();

    // ---- scalar PV (round-5 proven pattern; bf16 V^T vector loads) ----
    for (int pi = 0; pi < 4; pi++) {
        int idx = pi * 256 + tid;
        int row = idx >> 6, d = idx & 63;
        const short8* vp = (const short8*)(Vt + v_base + (size_t)d * S_LEN);
        float o = 0.f;
        for (int k8 = 0; k8 < S_LEN / 8; k8++) {
            short8 v8 = vp[k8];
#pragma unroll
            for (int j = 0; j < 8; j++)
                o += sc[row][k8 * 8 + j] * b2f(v8[j]);
        }
        float o2 = rowstat[row][1] * relv_s[0][d]
                 + rowstat[row][2] * relv_s[1][d]
                 + rowstat[row][3] * relv_s[2][d]
                 + rowstat[row][4] * relv_s[3][d]
                 + rowstat[row][5] * relv_s[4][d];
        Aout[(size_t)(q0 + row) * DM + col_base + hh * HD + d] =
            f2b((o + o2) * rowstat[row][0]);
    }
}

// ---------------------------------------------------------------------------
// out[b] = AO @ Wo + bo (round-5 proven; bf16 A loads, fp32 out).
// ---------------------------------------------------------------------------
__global__ __launch_bounds__(256) void outproj_scalar(
    const unsigned short* __restrict__ AO,
    const float* __restrict__ Wo,
    const float* __restrict__ bo,
    float* __restrict__ out,
    int b)
{
    __shared__ float As[64][17];
    __shared__ float Bs[16][65];

    int tid = threadIdx.x;
    int tx = tid & 15, ty = tid >> 4;
    int m0 = blockIdx.x * 64;
    int n0 = blockIdx.y * 64;

    float c[4][4];
#pragma unroll
    for (int i = 0; i < 4; i++)
#pragma unroll
        for (int j = 0; j < 4; j++) c[i][j] = 0.f;

    int ar = tid >> 2, ac = (tid & 3) * 4;
    for (int k0 = 0; k0 < DM; k0 += 16) {
#pragma unroll
        for (int j = 0; j < 4; j++)
            As[ar][ac + j] = b2f(AO[(size_t)(m0 + ar) * DM + k0 + ac + j]);
#pragma unroll
        for (int j = 0; j < 4; j++)
            Bs[ty][tx * 4 + j] = Wo[(size_t)(k0 + ty) * DM + n0 + tx * 4 + j];
        __syncthreads();
#pragma unroll
        for (int k = 0; k < 16; k++) {
            float a0 = As[ty * 4 + 0][k], a1 = As[ty * 4 + 1][k];
            float a2 = As[ty * 4 + 2][k], a3 = As[ty * 4 + 3][k];
            float b0 = Bs[k][tx * 4 + 0], b1 = Bs[k][tx * 4 + 1];
            float b2 = Bs[k][tx * 4 + 2], b3 = Bs[k][tx * 4 + 3];
            c[0][0] += a0 * b0; c[0][1] += a0 * b1; c[0][2] += a0 * b2; c[0][3] += a0 * b3;
            c[1][0] += a1 * b0; c[1][1] += a1 * b1; c[1][2] += a1 * b2; c[1][3] += a1 * b3;
            c[2][0] += a2 * b0; c[2][1] += a2 * b1; c[2][2] += a2 * b2; c[2][3] += a2 * b3;
            c[3][0] += a3 * b0; c[3][1] += a3 * b1; c[3][2] += a3 * b2; c[3][3] += a3 * b3;
        }
        __syncthreads();
    }

#pragma unroll
    for (int i = 0; i < 4; i++) {
        int m = m0 + ty * 4 + i;
#pragma unroll
        for (int j = 0; j < 4; j++) {
            int n = n0 + tx * 4 + j;
            out[((size_t)b * S_LEN + m) * DM + n] = c[i][j] + bo[n];
        }
    }
}

// ---------------------------------------------------------------------------
// Workspace (ushorts): 7.34 MB total, stream-ordered reuse.
// ---------------------------------------------------------------------------
extern "C" void kernel_launch(void* const* d_in, const int* in_sizes, int n_in,
                              void* d_out, int out_size, void* d_ws, size_t ws_size,
                              hipStream_t stream)
{
    const float* x  = (const float*)d_in[0];
    const float* Wq = (const float*)d_in[1];
    const float* bq = (const float*)d_in[2];
    const float* Wk = (const float*)d_in[3];
    const float* bk = (const float*)d_in[4];
    const float* Wv = (const float*)d_in[5];
    const float* bv = (const float*)d_in[6];
    const float* Wo = (const float*)d_in[7];
    const float* bo = (const float*)d_in[8];
    const float* rk = (const float*)d_in[9];
    const float* rv = (const float*)d_in[10];
    float* outp = (float*)d_out;

    unsigned short* ws  = (unsigned short*)d_ws;
    unsigned short* Qs  = ws;
    unsigned short* Ks  = ws + 524288;
    unsigned short* Vts = ws + 1048576;
    unsigned short* AOb = ws + 1572864;

    for (int b = 0; b < BATCH; b++) {
        for (int hg = 0; hg < 4; hg++) {
            proj_slice<<<dim3(32, 12), 256, 0, stream>>>(
                x, Wq, Wk, Wv, bq, bk, bv, Qs, Ks, Vts, b, hg);
            attn_hybrid<<<dim3(S_LEN / 16, 4), 256, 0, stream>>>(
                Qs, Ks, Vts, rk, rv, AOb, hg * 256);
        }
        outproj_scalar<<<dim3(32, 16), 256, 0, stream>>>(AOb, Wo, bo, outp, b);
    }
}

// Round 8
// 2197.926 us; speedup vs baseline: 5.0096x; 1.4868x over previous
//
#include <hip/hip_runtime.h>

// Problem: B=2, S=2048, Dm=1024, H=16, D=64, MAX_REL=2. Inputs/out fp32.
// Round 8: MFMA QK^T (verified r7) + MFMA PV with dedicated pbuf (no sc
// aliasing) + self-check/heal on both stages. proj/outproj: r5-proven scalar.
#define S_LEN 2048
#define DM    1024
#define NH    16
#define HD    64
#define BATCH 2
#define SPAD  2056

typedef __attribute__((ext_vector_type(8))) short short8;
typedef __attribute__((ext_vector_type(4))) float f32x4;

__device__ inline float b2f(unsigned short u) {
    return __uint_as_float(((unsigned)u) << 16);
}
__device__ inline unsigned short f2b(float f) {
    unsigned u = __float_as_uint(f);
    u += 0x7FFFu + ((u >> 16) & 1u);   // RNE
    return (unsigned short)(u >> 16);
}
__device__ inline f32x4 zero4() {
    f32x4 z; z[0] = 0.f; z[1] = 0.f; z[2] = 0.f; z[3] = 0.f; return z;
}

// ---------------------------------------------------------------------------
// QKV slice projection (round-5 proven math; bf16 stores).
// ---------------------------------------------------------------------------
__global__ __launch_bounds__(256) void proj_slice(
    const float* __restrict__ x,
    const float* __restrict__ Wq,
    const float* __restrict__ Wk,
    const float* __restrict__ Wv,
    const float* __restrict__ bq,
    const float* __restrict__ bk,
    const float* __restrict__ bv,
    unsigned short* __restrict__ Qs,   // [4][S][HD] bf16
    unsigned short* __restrict__ Ks,   // [4][S][HD] bf16
    unsigned short* __restrict__ Vts,  // [4][HD][S] bf16
    int b, int hg)
{
    __shared__ float As[64][17];
    __shared__ float Bs[16][65];

    int tid = threadIdx.x;
    int tx = tid & 15, ty = tid >> 4;
    int m0 = blockIdx.x * 64;
    int mat = blockIdx.y >> 2;
    int n0l = (blockIdx.y & 3) * 64;
    int gc0 = hg * 256 + n0l;

    const float* W    = (mat == 0) ? Wq : (mat == 1) ? Wk : Wv;
    const float* bias = (mat == 0) ? bq : (mat == 1) ? bk : bv;
    const float* xb = x + (size_t)b * S_LEN * DM;

    float c[4][4];
#pragma unroll
    for (int i = 0; i < 4; i++)
#pragma unroll
        for (int j = 0; j < 4; j++) c[i][j] = 0.f;

    int ar = tid >> 2, ac = (tid & 3) * 4;
    for (int k0 = 0; k0 < DM; k0 += 16) {
#pragma unroll
        for (int j = 0; j < 4; j++)
            As[ar][ac + j] = xb[(size_t)(m0 + ar) * DM + k0 + ac + j];
#pragma unroll
        for (int j = 0; j < 4; j++)
            Bs[ty][tx * 4 + j] = W[(size_t)(k0 + ty) * DM + gc0 + tx * 4 + j];
        __syncthreads();
#pragma unroll
        for (int k = 0; k < 16; k++) {
            float a0 = As[ty * 4 + 0][k], a1 = As[ty * 4 + 1][k];
            float a2 = As[ty * 4 + 2][k], a3 = As[ty * 4 + 3][k];
            float b0 = Bs[k][tx * 4 + 0], b1 = Bs[k][tx * 4 + 1];
            float b2 = Bs[k][tx * 4 + 2], b3 = Bs[k][tx * 4 + 3];
            c[0][0] += a0 * b0; c[0][1] += a0 * b1; c[0][2] += a0 * b2; c[0][3] += a0 * b3;
            c[1][0] += a1 * b0; c[1][1] += a1 * b1; c[1][2] += a1 * b2; c[1][3] += a1 * b3;
            c[2][0] += a2 * b0; c[2][1] += a2 * b1; c[2][2] += a2 * b2; c[2][3] += a2 * b3;
            c[3][0] += a3 * b0; c[3][1] += a3 * b1; c[3][2] += a3 * b2; c[3][3] += a3 * b3;
        }
        __syncthreads();
    }

#pragma unroll
    for (int i = 0; i < 4; i++) {
        int m = m0 + ty * 4 + i;
#pragma unroll
        for (int j = 0; j < 4; j++) {
            int nl = n0l + tx * 4 + j;
            float v = c[i][j] + bias[hg * 256 + nl];
            int hh = nl >> 6, d = nl & 63;
            if (mat == 2)
                Vts[((size_t)hh * HD + d) * S_LEN + m] = f2b(v);
            else if (mat == 0)
                Qs[((size_t)hh * S_LEN + m) * HD + d] = f2b(v);
            else
                Ks[((size_t)hh * S_LEN + m) * HD + d] = f2b(v);
        }
    }
}

// ---------------------------------------------------------------------------
// Attention: MFMA QK^T (r7-verified) + MFMA PV into dedicated pbuf, both with
// self-check + scalar heal. Proven softmax/bucket logic verbatim.
// ---------------------------------------------------------------------------
__global__ __launch_bounds__(256) void attn_mfma2(
    const unsigned short* __restrict__ Q,    // [4][S][HD] bf16
    const unsigned short* __restrict__ Km,   // [4][S][HD] bf16
    const unsigned short* __restrict__ Vt,   // [4][HD][S] bf16
    const float* __restrict__ relk,          // [5][64] fp32
    const float* __restrict__ relv,          // [5][64] fp32
    unsigned short* __restrict__ Aout,       // [S][DM] bf16 per-batch
    int col_base)
{
    __shared__ float sc[16][SPAD];           // 131.6 KB score rows
    __shared__ float pbuf[4][16][65];        // 16.6 KB PV partials (padded)
    __shared__ float qs[16][HD];             // 4 KB fp32 q-tile
    __shared__ float qrel_s[16][5];
    __shared__ float relv_s[5][HD];
    __shared__ float rowstat[16][8];
    __shared__ int   badflag, badflag2;

    int tid = threadIdx.x;
    int wave = tid >> 6, lane = tid & 63;
    int r = lane & 15, quad = lane >> 4;
    int q0 = blockIdx.x * 16;
    int hh = blockIdx.y;

    size_t qk_base = (size_t)hh * S_LEN * HD;
    size_t v_base  = (size_t)hh * HD * S_LEN;

    if (tid == 0) { badflag = 0; badflag2 = 0; }
    for (int i = tid; i < 16 * HD; i += 256)
        qs[i >> 6][i & 63] = b2f(Q[qk_base + (size_t)(q0 + (i >> 6)) * HD + (i & 63)]);
    for (int i = tid; i < 5 * HD; i += 256)
        relv_s[i >> 6][i & 63] = relv[i];

    // A-fragments: A[m=lane&15][k=quad*8+j]  (r7 hardware-verified)
    const short8* qp8 = (const short8*)(Q + qk_base + (size_t)(q0 + r) * HD + quad * 8);
    short8 aq0 = qp8[0];
    short8 aq1 = qp8[4];

    __syncthreads();   // qs ready

    if (tid < 80) {
        int row = tid / 5, j = tid % 5;
        float s = 0.f;
        for (int d = 0; d < HD; d++) s += qs[row][d] * relk[j * HD + d];
        qrel_s[row][j] = s;
    }

    // ---- QK^T via MFMA: wave w covers cols [w*512, (w+1)*512) ----
    for (int t = 0; t < 32; t++) {
        int n0 = wave * 512 + t * 16;
        const short8* kp = (const short8*)(Km + qk_base + (size_t)(n0 + r) * HD + quad * 8);
        short8 bk0 = kp[0];
        short8 bk1 = kp[4];
        f32x4 a1 = zero4();
        a1 = __builtin_amdgcn_mfma_f32_16x16x32_bf16(aq0, bk0, a1, 0, 0, 0);
        a1 = __builtin_amdgcn_mfma_f32_16x16x32_bf16(aq1, bk1, a1, 0, 0, 0);
#pragma unroll
        for (int i = 0; i < 4; i++) sc[quad * 4 + i][n0 + r] = a1[i];
    }
    __syncthreads();

    // ---- QK^T self-check (r7 pattern) ----
    if (tid < 16) {
        int row = tid;
        int col = (row * 131 + 37) & (S_LEN - 1);
        const unsigned short* kp = Km + qk_base + (size_t)col * HD;
        float sref = 0.f;
        for (int d = 0; d < HD; d++) sref += qs[row][d] * b2f(kp[d]);
        float got = sc[row][col];
        if (fabsf(sref - got) > 0.05f * (1.f + fabsf(sref))) badflag = 1;
    }
    __syncthreads();

    if (badflag) {   // heal: scalar scores
        for (int kk = 0; kk < 8; kk++) {
            int k = kk * 256 + tid;
            const short8* kp8 = (const short8*)(Km + qk_base + (size_t)k * HD);
            float s[16];
#pragma unroll
            for (int row = 0; row < 16; row++) s[row] = 0.f;
            for (int d8 = 0; d8 < 8; d8++) {
                short8 kv = kp8[d8];
                float kf[8];
#pragma unroll
                for (int j = 0; j < 8; j++) kf[j] = b2f(kv[j]);
#pragma unroll
                for (int row = 0; row < 16; row++)
#pragma unroll
                    for (int j = 0; j < 8; j++)
                        s[row] += qs[row][d8 * 8 + j] * kf[j];
            }
#pragma unroll
            for (int row = 0; row < 16; row++) sc[row][k] = s[row];
        }
        __syncthreads();
    }

    // ---- softmax + bucket sums (r5-proven) ----
    {
        int row = tid >> 4, c0 = tid & 15;
        int qglob = q0 + row;
        float mx = -1e30f;
        for (int c = c0; c < S_LEN; c += 16) {
            int del = min(2, max(-2, c - qglob));
            float s = (sc[row][c] + qrel_s[row][del + 2]) * 0.125f;
            sc[row][c] = s;
            mx = fmaxf(mx, s);
        }
#pragma unroll
        for (int off = 8; off > 0; off >>= 1) mx = fmaxf(mx, __shfl_xor(mx, off, 16));

        float denom = 0.f, suf = 0.f;
        for (int c = c0; c < S_LEN; c += 16) {
            float e = __expf(fminf(sc[row][c] - mx, 0.f));
            sc[row][c] = e;
            denom += e;
            if (c >= qglob + 2) suf += e;
        }
#pragma unroll
        for (int off = 8; off > 0; off >>= 1) {
            denom += __shfl_xor(denom, off, 16);
            suf   += __shfl_xor(suf,   off, 16);
        }
        if (c0 == 0) {
            float b1  = (qglob >= 1) ? sc[row][qglob - 1] : 0.f;
            float b2v = sc[row][qglob];
            float b3  = (qglob + 1 < S_LEN) ? sc[row][qglob + 1] : 0.f;
            float b0  = denom - suf - b1 - b2v - b3;
            rowstat[row][0] = 1.f / denom;
            rowstat[row][1] = b0;
            rowstat[row][2] = b1;
            rowstat[row][3] = b2v;
            rowstat[row][4] = b3;
            rowstat[row][5] = suf;
        }
    }
    __syncthreads();

    // ---- PV via MFMA: wave w covers k-chunk [w*512, (w+1)*512) ----
    f32x4 oacc[4];
#pragma unroll
    for (int nt = 0; nt < 4; nt++) oacc[nt] = zero4();

    for (int st = 0; st < 16; st++) {
        int kk = wave * 512 + st * 32;
        const float* prow = &sc[r][kk + quad * 8];
        short8 af;
#pragma unroll
        for (int j = 0; j < 8; j++) af[j] = (short)f2b(prow[j]);
#pragma unroll
        for (int nt = 0; nt < 4; nt++) {
            short8 bv = *(const short8*)(Vt + v_base + (size_t)(nt * 16 + r) * S_LEN + kk + quad * 8);
            oacc[nt] = __builtin_amdgcn_mfma_f32_16x16x32_bf16(af, bv, oacc[nt], 0, 0, 0);
        }
    }
    // pbuf is a SEPARATE buffer (no sc aliasing): write partials directly
#pragma unroll
    for (int nt = 0; nt < 4; nt++)
#pragma unroll
        for (int i = 0; i < 4; i++)
            pbuf[wave][quad * 4 + i][nt * 16 + r] = oacc[nt][i];
    __syncthreads();

    // ---- PV self-check: 16 sampled outputs vs scalar recompute from sc ----
    if (tid < 16) {
        int row = tid;
        int d = (row * 37 + 11) & 63;
        const unsigned short* vp = Vt + v_base + (size_t)d * S_LEN;
        float oref = 0.f;
        for (int k = 0; k < S_LEN; k++)
            oref += b2f(f2b(sc[row][k])) * b2f(vp[k]);
        float got = pbuf[0][row][d] + pbuf[1][row][d] + pbuf[2][row][d] + pbuf[3][row][d];
        if (fabsf(oref - got) > 0.05f * (1.f + fabsf(oref))) badflag2 = 1;
    }
    __syncthreads();

    if (badflag2) {  // heal: full scalar PV into pbuf[0], zero others
        for (int pi = 0; pi < 4; pi++) {
            int idx = pi * 256 + tid;
            int row = idx >> 6, d = idx & 63;
            const short8* vp = (const short8*)(Vt + v_base + (size_t)d * S_LEN);
            float o = 0.f;
            for (int k8 = 0; k8 < S_LEN / 8; k8++) {
                short8 v8 = vp[k8];
#pragma unroll
                for (int j = 0; j < 8; j++)
                    o += sc[row][k8 * 8 + j] * b2f(v8[j]);
            }
            pbuf[0][row][d] = o;
            pbuf[1][row][d] = 0.f;
            pbuf[2][row][d] = 0.f;
            pbuf[3][row][d] = 0.f;
        }
        __syncthreads();
    }

    // ---- epilogue: reduce partials + rel_v bucket term + normalize ----
    for (int oidx = tid; oidx < 1024; oidx += 256) {
        int orow = oidx >> 6, ocol = oidx & 63;
        float o = pbuf[0][orow][ocol] + pbuf[1][orow][ocol]
                + pbuf[2][orow][ocol] + pbuf[3][orow][ocol];
        float o2 = rowstat[orow][1] * relv_s[0][ocol]
                 + rowstat[orow][2] * relv_s[1][ocol]
                 + rowstat[orow][3] * relv_s[2][ocol]
                 + rowstat[orow][4] * relv_s[3][ocol]
                 + rowstat[orow][5] * relv_s[4][ocol];
        float res = (o + o2) * rowstat[orow][0];
        Aout[(size_t)(q0 + orow) * DM + col_base + hh * HD + ocol] = f2b(res);
    }
}

// ---------------------------------------------------------------------------
// out[b] = AO @ Wo + bo (r5-proven; bf16 A loads, fp32 out).
// ---------------------------------------------------------------------------
__global__ __launch_bounds__(256) void outproj_scalar(
    const unsigned short* __restrict__ AO,
    const float* __restrict__ Wo,
    const float* __restrict__ bo,
    float* __restrict__ out,
    int b)
{
    __shared__ float As[64][17];
    __shared__ float Bs[16][65];

    int tid = threadIdx.x;
    int tx = tid & 15, ty = tid >> 4;
    int m0 = blockIdx.x * 64;
    int n0 = blockIdx.y * 64;

    float c[4][4];
#pragma unroll
    for (int i = 0; i < 4; i++)
#pragma unroll
        for (int j = 0; j < 4; j++) c[i][j] = 0.f;

    int ar = tid >> 2, ac = (tid & 3) * 4;
    for (int k0 = 0; k0 < DM; k0 += 16) {
#pragma unroll
        for (int j = 0; j < 4; j++)
            As[ar][ac + j] = b2f(AO[(size_t)(m0 + ar) * DM + k0 + ac + j]);
#pragma unroll
        for (int j = 0; j < 4; j++)
            Bs[ty][tx * 4 + j] = Wo[(size_t)(k0 + ty) * DM + n0 + tx * 4 + j];
        __syncthreads();
#pragma unroll
        for (int k = 0; k < 16; k++) {
            float a0 = As[ty * 4 + 0][k], a1 = As[ty * 4 + 1][k];
            float a2 = As[ty * 4 + 2][k], a3 = As[ty * 4 + 3][k];
            float b0 = Bs[k][tx * 4 + 0], b1 = Bs[k][tx * 4 + 1];
            float b2 = Bs[k][tx * 4 + 2], b3 = Bs[k][tx * 4 + 3];
            c[0][0] += a0 * b0; c[0][1] += a0 * b1; c[0][2] += a0 * b2; c[0][3] += a0 * b3;
            c[1][0] += a1 * b0; c[1][1] += a1 * b1; c[1][2] += a1 * b2; c[1][3] += a1 * b3;
            c[2][0] += a2 * b0; c[2][1] += a2 * b1; c[2][2] += a2 * b2; c[2][3] += a2 * b3;
            c[3][0] += a3 * b0; c[3][1] += a3 * b1; c[3][2] += a3 * b2; c[3][3] += a3 * b3;
        }
        __syncthreads();
    }

#pragma unroll
    for (int i = 0; i < 4; i++) {
        int m = m0 + ty * 4 + i;
#pragma unroll
        for (int j = 0; j < 4; j++) {
            int n = n0 + tx * 4 + j;
            out[((size_t)b * S_LEN + m) * DM + n] = c[i][j] + bo[n];
        }
    }
}

// ---------------------------------------------------------------------------
// Workspace (ushorts): 7.34 MB total, stream-ordered reuse.
// ---------------------------------------------------------------------------
extern "C" void kernel_launch(void* const* d_in, const int* in_sizes, int n_in,
                              void* d_out, int out_size, void* d_ws, size_t ws_size,
                              hipStream_t stream)
{
    const float* x  = (const float*)d_in[0];
    const float* Wq = (const float*)d_in[1];
    const float* bq = (const float*)d_in[2];
    const float* Wk = (const float*)d_in[3];
    const float* bk = (const float*)d_in[4];
    const float* Wv = (const float*)d_in[5];
    const float* bv = (const float*)d_in[6];
    const float* Wo = (const float*)d_in[7];
    const float* bo = (const float*)d_in[8];
    const float* rk = (const float*)d_in[9];
    const float* rv = (const float*)d_in[10];
    float* outp = (float*)d_out;

    unsigned short* ws  = (unsigned short*)d_ws;
    unsigned short* Qs  = ws;
    unsigned short* Ks  = ws + 524288;
    unsigned short* Vts = ws + 1048576;
    unsigned short* AOb = ws + 1572864;

    for (int b = 0; b < BATCH; b++) {
        for (int hg = 0; hg < 4; hg++) {
            proj_slice<<<dim3(32, 12), 256, 0, stream>>>(
                x, Wq, Wk, Wv, bq, bk, bv, Qs, Ks, Vts, b, hg);
            attn_mfma2<<<dim3(S_LEN / 16, 4), 256, 0, stream>>>(
                Qs, Ks, Vts, rk, rv, AOb, hg * 256);
        }
        outproj_scalar<<<dim3(32, 16), 256, 0, stream>>>(AOb, Wo, bo, outp, b);
    }
}

// Round 9
// 897.760 us; speedup vs baseline: 12.2646x; 2.4482x over previous
//
#include <hip/hip_runtime.h>

// Problem: B=2, S=2048, Dm=1024, H=16, D=64, MAX_REL=2. Inputs/out fp32.
// Round 9: all-MFMA pipeline. Conventions HW-verified r7/r8:
//   A[m=lane&15][k=quad*8+j], B[n=lane&15][k=quad*8+j], D[m=quad*4+i][n=lane&15]
// attn: 1024-thread blocks (16 waves), dedicated pbuf (r6 bug: sc aliasing).
#define S_LEN 2048
#define DM    1024
#define NH    16
#define HD    64
#define BATCH 2
#define SPAD  2056

typedef __attribute__((ext_vector_type(8))) short short8;
typedef __attribute__((ext_vector_type(4))) float f32x4;
typedef __attribute__((ext_vector_type(4))) unsigned short u16x4;

__device__ inline float b2f(unsigned short u) {
    return __uint_as_float(((unsigned)u) << 16);
}
__device__ inline unsigned short f2b(float f) {
    unsigned u = __float_as_uint(f);
    u += 0x7FFFu + ((u >> 16) & 1u);   // RNE
    return (unsigned short)(u >> 16);
}
__device__ inline f32x4 zero4() {
    f32x4 z; z[0] = 0.f; z[1] = 0.f; z[2] = 0.f; z[3] = 0.f; return z;
}

// ---------------------------------------------------------------------------
// x fp32 -> bf16, 4 elems/thread.
// ---------------------------------------------------------------------------
__global__ __launch_bounds__(256) void cvt_x(
    const float* __restrict__ src, unsigned short* __restrict__ dst, int n4)
{
    int i = blockIdx.x * 256 + threadIdx.x;
    if (i >= n4) return;
    f32x4 v = ((const f32x4*)src)[i];
    u16x4 o;
    o[0] = f2b(v[0]); o[1] = f2b(v[1]); o[2] = f2b(v[2]); o[3] = f2b(v[3]);
    ((u16x4*)dst)[i] = o;
}

// ---------------------------------------------------------------------------
// Wq/Wk/Wv hg-column-slices -> transposed bf16 Wtc[3][256][1024] (n-major).
// grid (32 k-tiles, 8 n-tiles, 3 mats), block (32,8).
// ---------------------------------------------------------------------------
__global__ __launch_bounds__(256) void cvt_wslice(
    const float* __restrict__ Wq, const float* __restrict__ Wk,
    const float* __restrict__ Wv, unsigned short* __restrict__ Wtc, int hg)
{
    __shared__ unsigned short tile[32][33];
    int mat = blockIdx.z;
    const float* W = (mat == 0) ? Wq : (mat == 1) ? Wk : Wv;
    int tx = threadIdx.x, ty = threadIdx.y;
    int k0 = blockIdx.x * 32, n0 = blockIdx.y * 32;
#pragma unroll
    for (int i = 0; i < 4; i++)
        tile[ty + 8 * i][tx] = f2b(W[(size_t)(k0 + ty + 8 * i) * DM + hg * 256 + n0 + tx]);
    __syncthreads();
    unsigned short* dst = Wtc + (size_t)mat * 262144;
#pragma unroll
    for (int i = 0; i < 4; i++)
        dst[(size_t)(n0 + ty + 8 * i) * 1024 + k0 + tx] = tile[tx][ty + 8 * i];
}

// ---------------------------------------------------------------------------
// Wo -> transposed bf16 [1024][1024]. grid (32,32), block (32,8).
// ---------------------------------------------------------------------------
__global__ __launch_bounds__(256) void cvt_wo(
    const float* __restrict__ Wo, unsigned short* __restrict__ Wtoc)
{
    __shared__ unsigned short tile[32][33];
    int tx = threadIdx.x, ty = threadIdx.y;
    int k0 = blockIdx.x * 32, n0 = blockIdx.y * 32;
#pragma unroll
    for (int i = 0; i < 4; i++)
        tile[ty + 8 * i][tx] = f2b(Wo[(size_t)(k0 + ty + 8 * i) * DM + n0 + tx]);
    __syncthreads();
#pragma unroll
    for (int i = 0; i < 4; i++)
        Wtoc[(size_t)(n0 + ty + 8 * i) * 1024 + k0 + tx] = tile[tx][ty + 8 * i];
}

// ---------------------------------------------------------------------------
// QKV slice projection via MFMA (r7-verified pattern). grid (32,12), 256 thr.
// ---------------------------------------------------------------------------
__global__ __launch_bounds__(256) void proj_mfma(
    const unsigned short* __restrict__ xc,   // [S][DM] bf16
    const unsigned short* __restrict__ Wtc,  // [3][256][1024] bf16
    const float* __restrict__ bq, const float* __restrict__ bk,
    const float* __restrict__ bv,
    unsigned short* __restrict__ Qs, unsigned short* __restrict__ Ks,
    unsigned short* __restrict__ Vts, int hg)
{
    int wave = threadIdx.x >> 6, lane = threadIdx.x & 63;
    int r = lane & 15, quad = lane >> 4;
    int m0 = blockIdx.x * 64 + wave * 16;
    int mat = blockIdx.y >> 2;
    int n0l = (blockIdx.y & 3) * 64;

    const unsigned short* Wt = Wtc + (size_t)mat * 262144;
    const float* bias = (mat == 0) ? bq : (mat == 1) ? bk : bv;

    f32x4 acc[4];
#pragma unroll
    for (int nt = 0; nt < 4; nt++) acc[nt] = zero4();

    const short8* ap = (const short8*)(xc + (size_t)(m0 + r) * DM + quad * 8);
    const short8* bp[4];
#pragma unroll
    for (int nt = 0; nt < 4; nt++)
        bp[nt] = (const short8*)(Wt + (size_t)(n0l + nt * 16 + r) * 1024 + quad * 8);

    for (int k0 = 0; k0 < DM; k0 += 32) {
        short8 a = *ap; ap += 4;
#pragma unroll
        for (int nt = 0; nt < 4; nt++) {
            short8 bfr = *bp[nt]; bp[nt] += 4;
            acc[nt] = __builtin_amdgcn_mfma_f32_16x16x32_bf16(a, bfr, acc[nt], 0, 0, 0);
        }
    }

#pragma unroll
    for (int nt = 0; nt < 4; nt++) {
        int nl = n0l + nt * 16 + r;
        int hh = nl >> 6, d = nl & 63;
        float bb = bias[hg * 256 + nl];
#pragma unroll
        for (int i = 0; i < 4; i++) {
            int s = m0 + quad * 4 + i;
            float v = acc[nt][i] + bb;
            if (mat == 2)
                Vts[((size_t)hh * HD + d) * S_LEN + s] = f2b(v);
            else if (mat == 0)
                Qs[((size_t)hh * S_LEN + s) * HD + d] = f2b(v);
            else
                Ks[((size_t)hh * S_LEN + s) * HD + d] = f2b(v);
        }
    }
}

// ---------------------------------------------------------------------------
// Fused relative attention, 1024 threads = 16 waves, 1 block = (hh, 16 rows).
// QK^T: wave w -> cols [w*128,(w+1)*128). Softmax: wave w -> row w.
// PV: wave w -> (d-tile w&3, k-chunk w>>2), partials in dedicated pbuf.
// ---------------------------------------------------------------------------
__global__ __launch_bounds__(1024) void attn_mfma(
    const unsigned short* __restrict__ Q,    // [4][S][HD] bf16
    const unsigned short* __restrict__ Km,   // [4][S][HD] bf16
    const unsigned short* __restrict__ Vt,   // [4][HD][S] bf16
    const float* __restrict__ relk,          // [5][64] fp32
    const float* __restrict__ relv,          // [5][64] fp32
    unsigned short* __restrict__ Aout,       // [S][DM] bf16 per-batch
    int col_base)
{
    __shared__ float sc[16][SPAD];           // 131.6 KB score rows
    __shared__ float pbuf[4][16][65];        // 16.6 KB PV partials (dedicated!)
    __shared__ float qs[16][HD];             // 4 KB fp32 q-tile
    __shared__ float qrel_s[16][5];
    __shared__ float relv_s[5][HD];
    __shared__ float rowstat[16][8];

    int tid = threadIdx.x;
    int wave = tid >> 6, lane = tid & 63;
    int r = lane & 15, quad = lane >> 4;
    int q0 = blockIdx.x * 16;
    int hh = blockIdx.y;

    size_t qk_base = (size_t)hh * S_LEN * HD;
    size_t v_base  = (size_t)hh * HD * S_LEN;

    // stage q-tile fp32 (1024 elems = 1/thread) + relv
    qs[tid >> 6][tid & 63] = b2f(Q[qk_base + (size_t)(q0 + (tid >> 6)) * HD + (tid & 63)]);
    if (tid < 5 * HD) relv_s[tid >> 6][tid & 63] = relv[tid];

    // A-fragments (same for all waves)
    const short8* qp8 = (const short8*)(Q + qk_base + (size_t)(q0 + r) * HD + quad * 8);
    short8 aq0 = qp8[0];
    short8 aq1 = qp8[4];

    __syncthreads();

    if (tid < 80) {
        int row = tid / 5, j = tid % 5;
        float s = 0.f;
        for (int d = 0; d < HD; d++) s += qs[row][d] * relk[j * HD + d];
        qrel_s[row][j] = s;
    }

    // ---- QK^T: 8 iters/wave ----
    for (int t = 0; t < 8; t++) {
        int n0 = wave * 128 + t * 16;
        const short8* kp = (const short8*)(Km + qk_base + (size_t)(n0 + r) * HD + quad * 8);
        short8 bk0 = kp[0];
        short8 bk1 = kp[4];
        f32x4 a1 = zero4();
        a1 = __builtin_amdgcn_mfma_f32_16x16x32_bf16(aq0, bk0, a1, 0, 0, 0);
        a1 = __builtin_amdgcn_mfma_f32_16x16x32_bf16(aq1, bk1, a1, 0, 0, 0);
#pragma unroll
        for (int i = 0; i < 4; i++) sc[quad * 4 + i][n0 + r] = a1[i];
    }
    __syncthreads();

    // ---- softmax + buckets: one wave per row (r5-proven math) ----
    {
        int row = wave;
        int qglob = q0 + row;
        float mx = -1e30f;
        for (int c = lane; c < S_LEN; c += 64) {
            int del = min(2, max(-2, c - qglob));
            float s = (sc[row][c] + qrel_s[row][del + 2]) * 0.125f;   // /sqrt(64)
            sc[row][c] = s;
            mx = fmaxf(mx, s);
        }
#pragma unroll
        for (int off = 32; off > 0; off >>= 1) mx = fmaxf(mx, __shfl_xor(mx, off));

        float denom = 0.f, suf = 0.f;
        for (int c = lane; c < S_LEN; c += 64) {
            float e = __expf(fminf(sc[row][c] - mx, 0.f));
            sc[row][c] = e;
            denom += e;
            if (c >= qglob + 2) suf += e;
        }
#pragma unroll
        for (int off = 32; off > 0; off >>= 1) {
            denom += __shfl_xor(denom, off);
            suf   += __shfl_xor(suf, off);
        }
        if (lane == 0) {
            float b1  = (qglob >= 1) ? sc[row][qglob - 1] : 0.f;
            float b2v = sc[row][qglob];
            float b3  = (qglob + 1 < S_LEN) ? sc[row][qglob + 1] : 0.f;
            rowstat[row][0] = 1.f / denom;
            rowstat[row][1] = denom - suf - b1 - b2v - b3;   // bucket 0 (k<=q-2)
            rowstat[row][2] = b1;
            rowstat[row][3] = b2v;
            rowstat[row][4] = b3;
            rowstat[row][5] = suf;                           // bucket 4 (k>=q+2)
        }
    }
    __syncthreads();

    // ---- PV: wave w -> (nt = w&3, kc = w>>2), 16 MFMAs ----
    {
        int nt = wave & 3, kc = wave >> 2;
        f32x4 oacc = zero4();
        const unsigned short* vrow = Vt + v_base + (size_t)(nt * 16 + r) * S_LEN;
        for (int st = 0; st < 16; st++) {
            int kk = kc * 512 + st * 32;
            const f32x4* pv = (const f32x4*)&sc[r][kk + quad * 8];
            f32x4 p0 = pv[0], p1 = pv[1];
            short8 af;
            af[0] = (short)f2b(p0[0]); af[1] = (short)f2b(p0[1]);
            af[2] = (short)f2b(p0[2]); af[3] = (short)f2b(p0[3]);
            af[4] = (short)f2b(p1[0]); af[5] = (short)f2b(p1[1]);
            af[6] = (short)f2b(p1[2]); af[7] = (short)f2b(p1[3]);
            short8 bv = *(const short8*)(vrow + kk + quad * 8);
            oacc = __builtin_amdgcn_mfma_f32_16x16x32_bf16(af, bv, oacc, 0, 0, 0);
        }
#pragma unroll
        for (int i = 0; i < 4; i++)
            pbuf[kc][quad * 4 + i][nt * 16 + r] = oacc[i];
    }
    __syncthreads();

    // ---- epilogue: 1024 outputs, one per thread ----
    {
        int orow = tid >> 6, ocol = tid & 63;
        float o = pbuf[0][orow][ocol] + pbuf[1][orow][ocol]
                + pbuf[2][orow][ocol] + pbuf[3][orow][ocol];
        float o2 = rowstat[orow][1] * relv_s[0][ocol]
                 + rowstat[orow][2] * relv_s[1][ocol]
                 + rowstat[orow][3] * relv_s[2][ocol]
                 + rowstat[orow][4] * relv_s[3][ocol]
                 + rowstat[orow][5] * relv_s[4][ocol];
        float res = (o + o2) * rowstat[orow][0];
        Aout[(size_t)(q0 + orow) * DM + col_base + hh * HD + ocol] = f2b(res);
    }
}

// ---------------------------------------------------------------------------
// out[b] = AO @ Wo + bo via MFMA (verified pattern), fp32 out. grid (32,16).
// ---------------------------------------------------------------------------
__global__ __launch_bounds__(256) void outproj_mfma(
    const unsigned short* __restrict__ AO,    // [S][DM] bf16
    const unsigned short* __restrict__ Wtoc,  // [1024][1024] bf16 n-major
    const float* __restrict__ bo,
    float* __restrict__ out, int b)
{
    int wave = threadIdx.x >> 6, lane = threadIdx.x & 63;
    int r = lane & 15, quad = lane >> 4;
    int m0 = blockIdx.x * 64 + wave * 16;
    int n0 = blockIdx.y * 64;

    f32x4 acc[4];
#pragma unroll
    for (int nt = 0; nt < 4; nt++) acc[nt] = zero4();

    const short8* ap = (const short8*)(AO + (size_t)(m0 + r) * DM + quad * 8);
    const short8* bp[4];
#pragma unroll
    for (int nt = 0; nt < 4; nt++)
        bp[nt] = (const short8*)(Wtoc + (size_t)(n0 + nt * 16 + r) * 1024 + quad * 8);

    for (int k0 = 0; k0 < DM; k0 += 32) {
        short8 a = *ap; ap += 4;
#pragma unroll
        for (int nt = 0; nt < 4; nt++) {
            short8 bfr = *bp[nt]; bp[nt] += 4;
            acc[nt] = __builtin_amdgcn_mfma_f32_16x16x32_bf16(a, bfr, acc[nt], 0, 0, 0);
        }
    }

#pragma unroll
    for (int nt = 0; nt < 4; nt++) {
        int n = n0 + nt * 16 + r;
        float bb = bo[n];
#pragma unroll
        for (int i = 0; i < 4; i++) {
            int m = m0 + quad * 4 + i;
            out[((size_t)b * S_LEN + m) * DM + n] = acc[nt][i] + bb;
        }
    }
}

// ---------------------------------------------------------------------------
// Workspace (ushorts), total 12.5 MB (proven budget 14 MB):
//   xc   [0, 2097152)        x bf16 per batch; Wtoc overlays [0, 1048576)
//   Wtc  [2097152, 2883584)  per-hg W slices [3][256][1024]
//   Qs   [2883584, 3407872)  Ks +524288  Vts +524288
//   AOb  [4456448, 6553600)
// All overlays stream-ordered (xc dead before cvt_wo; Wtoc dead before cvt_x).
// ---------------------------------------------------------------------------
extern "C" void kernel_launch(void* const* d_in, const int* in_sizes, int n_in,
                              void* d_out, int out_size, void* d_ws, size_t ws_size,
                              hipStream_t stream)
{
    const float* x  = (const float*)d_in[0];
    const float* Wq = (const float*)d_in[1];
    const float* bq = (const float*)d_in[2];
    const float* Wk = (const float*)d_in[3];
    const float* bk = (const float*)d_in[4];
    const float* Wv = (const float*)d_in[5];
    const float* bv = (const float*)d_in[6];
    const float* Wo = (const float*)d_in[7];
    const float* bo = (const float*)d_in[8];
    const float* rk = (const float*)d_in[9];
    const float* rv = (const float*)d_in[10];
    float* outp = (float*)d_out;

    unsigned short* ws   = (unsigned short*)d_ws;
    unsigned short* xc   = ws;
    unsigned short* Wtoc = ws;                 // overlays xc (stream-ordered)
    unsigned short* Wtc  = ws + 2097152;
    unsigned short* Qs   = ws + 2883584;
    unsigned short* Ks   = ws + 3407872;
    unsigned short* Vts  = ws + 3932160;
    unsigned short* AOb  = ws + 4456448;

    for (int b = 0; b < BATCH; b++) {
        cvt_x<<<2048, 256, 0, stream>>>(x + (size_t)b * S_LEN * DM, xc, 524288);
        for (int hg = 0; hg < 4; hg++) {
            cvt_wslice<<<dim3(32, 8, 3), dim3(32, 8), 0, stream>>>(Wq, Wk, Wv, Wtc, hg);
            proj_mfma<<<dim3(32, 12), 256, 0, stream>>>(
                xc, Wtc, bq, bk, bv, Qs, Ks, Vts, hg);
            attn_mfma<<<dim3(S_LEN / 16, 4), 1024, 0, stream>>>(
                Qs, Ks, Vts, rk, rv, AOb, hg * 256);
        }
        cvt_wo<<<dim3(32, 32), dim3(32, 8), 0, stream>>>(Wo, Wtoc);
        outproj_mfma<<<dim3(32, 16), 256, 0, stream>>>(AOb, Wtoc, bo, outp, b);
    }
}

// Round 10
// 675.929 us; speedup vs baseline: 16.2897x; 1.3282x over previous
//
#include <hip/hip_runtime.h>

// Problem: B=2, S=2048, Dm=1024, H=16, D=64, MAX_REL=2. Inputs/out fp32.
// Round 10: fused GEMMs (LDS-staged fp32->bf16 W transpose, no cvt kernels,
// no weight buffers) + ws-adaptive head grouping. MFMA conventions HW-verified
// r7/r8: A[m=lane&15][k=quad*8+j], B[n=lane&15][k=quad*8+j], D[m=quad*4+i][n=lane&15].
#define S_LEN 2048
#define DM    1024
#define NH    16
#define HD    64
#define BATCH 2
#define SPAD  2056

typedef __attribute__((ext_vector_type(8))) short short8;
typedef __attribute__((ext_vector_type(4))) float f32x4;

__device__ inline float b2f(unsigned short u) {
    return __uint_as_float(((unsigned)u) << 16);
}
__device__ inline unsigned short f2b(float f) {
    unsigned u = __float_as_uint(f);
    u += 0x7FFFu + ((u >> 16) & 1u);   // RNE
    return (unsigned short)(u >> 16);
}
__device__ inline f32x4 zero4() {
    f32x4 z; z[0] = 0.f; z[1] = 0.f; z[2] = 0.f; z[3] = 0.f; return z;
}

// ---------------------------------------------------------------------------
// Fused QKV projection: A = x fp32 (reg-converted), B = W fp32 staged through
// LDS (transpose + bf16). Block: 64(M)x64(N), 4 waves, wave = 16x64.
// grid (32, 3*NG): mat = y/NG, hh = y%NG; cols = (head0+hh)*64 .. +64.
// ---------------------------------------------------------------------------
__global__ __launch_bounds__(256) void proj_fused(
    const float* __restrict__ x,     // [B][S][DM] fp32
    const float* __restrict__ Wq, const float* __restrict__ Wk,
    const float* __restrict__ Wv,
    const float* __restrict__ bq, const float* __restrict__ bk,
    const float* __restrict__ bv,
    unsigned short* __restrict__ Qs,   // [NG][S][HD] bf16
    unsigned short* __restrict__ Ks,   // [NG][S][HD] bf16
    unsigned short* __restrict__ Vts,  // [NG][HD][S] bf16
    int b, int head0, int NG)
{
    __shared__ unsigned short Bs[64][72];   // [n][k] bf16, pad->balanced banks

    int tid = threadIdx.x;
    int wave = tid >> 6, lane = tid & 63;
    int r = lane & 15, quad = lane >> 4;
    int m0 = blockIdx.x * 64 + wave * 16;
    int mat = blockIdx.y / NG;
    int hh  = blockIdx.y % NG;
    int gc0 = (head0 + hh) * 64;

    const float* W    = (mat == 0) ? Wq : (mat == 1) ? Wk : Wv;
    const float* bias = (mat == 0) ? bq : (mat == 1) ? bk : bv;
    const float* xb = x + (size_t)b * S_LEN * DM;

    f32x4 acc[4];
#pragma unroll
    for (int nt = 0; nt < 4; nt++) acc[nt] = zero4();

    int kr = tid >> 2;            // 0..63 : W row within k-tile
    int nc = (tid & 3) * 16;      // 0/16/32/48 : col chunk

    const float* am = xb + (size_t)(m0 + r) * DM + quad * 8;

    for (int k0 = 0; k0 < DM; k0 += 64) {
        // prefetch W tile (no Bs access yet)
        const f32x4* wr = (const f32x4*)(W + (size_t)(k0 + kr) * DM + gc0 + nc);
        f32x4 w0 = wr[0], w1 = wr[1], w2 = wr[2], w3 = wr[3];
        __syncthreads();          // previous iter's Bs reads complete
        Bs[nc +  0][kr] = f2b(w0[0]); Bs[nc +  1][kr] = f2b(w0[1]);
        Bs[nc +  2][kr] = f2b(w0[2]); Bs[nc +  3][kr] = f2b(w0[3]);
        Bs[nc +  4][kr] = f2b(w1[0]); Bs[nc +  5][kr] = f2b(w1[1]);
        Bs[nc +  6][kr] = f2b(w1[2]); Bs[nc +  7][kr] = f2b(w1[3]);
        Bs[nc +  8][kr] = f2b(w2[0]); Bs[nc +  9][kr] = f2b(w2[1]);
        Bs[nc + 10][kr] = f2b(w2[2]); Bs[nc + 11][kr] = f2b(w2[3]);
        Bs[nc + 12][kr] = f2b(w3[0]); Bs[nc + 13][kr] = f2b(w3[1]);
        Bs[nc + 14][kr] = f2b(w3[2]); Bs[nc + 15][kr] = f2b(w3[3]);
        __syncthreads();          // Bs visible

#pragma unroll
        for (int ks = 0; ks < 2; ks++) {
            const f32x4* ap = (const f32x4*)(am + k0 + ks * 32);
            f32x4 a0 = ap[0], a1 = ap[1];
            short8 a;
            a[0] = (short)f2b(a0[0]); a[1] = (short)f2b(a0[1]);
            a[2] = (short)f2b(a0[2]); a[3] = (short)f2b(a0[3]);
            a[4] = (short)f2b(a1[0]); a[5] = (short)f2b(a1[1]);
            a[6] = (short)f2b(a1[2]); a[7] = (short)f2b(a1[3]);
#pragma unroll
            for (int nt = 0; nt < 4; nt++) {
                short8 bf = *(const short8*)&Bs[nt * 16 + r][ks * 32 + quad * 8];
                acc[nt] = __builtin_amdgcn_mfma_f32_16x16x32_bf16(a, bf, acc[nt], 0, 0, 0);
            }
        }
    }

#pragma unroll
    for (int nt = 0; nt < 4; nt++) {
        int d = nt * 16 + r;                  // col within head = head-dim
        float bb = bias[gc0 + d];
#pragma unroll
        for (int i = 0; i < 4; i++) {
            int s = m0 + quad * 4 + i;
            float v = acc[nt][i] + bb;
            if (mat == 2)
                Vts[((size_t)hh * HD + d) * S_LEN + s] = f2b(v);
            else if (mat == 0)
                Qs[((size_t)hh * S_LEN + s) * HD + d] = f2b(v);
            else
                Ks[((size_t)hh * S_LEN + s) * HD + d] = f2b(v);
        }
    }
}

// ---------------------------------------------------------------------------
// Fused relative attention (r9-verified, unchanged math). 1024 thr = 16 waves.
// One block = (head hh, 16-row q-tile). Dedicated pbuf (r6 bug: sc aliasing).
// ---------------------------------------------------------------------------
__global__ __launch_bounds__(1024) void attn_mfma(
    const unsigned short* __restrict__ Q,    // [NG][S][HD] bf16
    const unsigned short* __restrict__ Km,   // [NG][S][HD] bf16
    const unsigned short* __restrict__ Vt,   // [NG][HD][S] bf16
    const float* __restrict__ relk,          // [5][64] fp32
    const float* __restrict__ relv,          // [5][64] fp32
    unsigned short* __restrict__ Aout,       // [S][DM] bf16 per-batch
    int col_base)                            // head0*64
{
    __shared__ float sc[16][SPAD];           // 131.6 KB score rows
    __shared__ float pbuf[4][16][65];        // 16.6 KB PV partials (dedicated)
    __shared__ float qs[16][HD];
    __shared__ float qrel_s[16][5];
    __shared__ float relv_s[5][HD];
    __shared__ float rowstat[16][8];

    int tid = threadIdx.x;
    int wave = tid >> 6, lane = tid & 63;
    int r = lane & 15, quad = lane >> 4;
    int q0 = blockIdx.x * 16;
    int hh = blockIdx.y;

    size_t qk_base = (size_t)hh * S_LEN * HD;
    size_t v_base  = (size_t)hh * HD * S_LEN;

    qs[tid >> 6][tid & 63] = b2f(Q[qk_base + (size_t)(q0 + (tid >> 6)) * HD + (tid & 63)]);
    if (tid < 5 * HD) relv_s[tid >> 6][tid & 63] = relv[tid];

    const short8* qp8 = (const short8*)(Q + qk_base + (size_t)(q0 + r) * HD + quad * 8);
    short8 aq0 = qp8[0];
    short8 aq1 = qp8[4];

    __syncthreads();

    if (tid < 80) {
        int row = tid / 5, j = tid % 5;
        float s = 0.f;
        for (int d = 0; d < HD; d++) s += qs[row][d] * relk[j * HD + d];
        qrel_s[row][j] = s;
    }

    // ---- QK^T: 8 iters/wave ----
    for (int t = 0; t < 8; t++) {
        int n0 = wave * 128 + t * 16;
        const short8* kp = (const short8*)(Km + qk_base + (size_t)(n0 + r) * HD + quad * 8);
        short8 bk0 = kp[0];
        short8 bk1 = kp[4];
        f32x4 a1 = zero4();
        a1 = __builtin_amdgcn_mfma_f32_16x16x32_bf16(aq0, bk0, a1, 0, 0, 0);
        a1 = __builtin_amdgcn_mfma_f32_16x16x32_bf16(aq1, bk1, a1, 0, 0, 0);
#pragma unroll
        for (int i = 0; i < 4; i++) sc[quad * 4 + i][n0 + r] = a1[i];
    }
    __syncthreads();

    // ---- softmax + buckets: one wave per row ----
    {
        int row = wave;
        int qglob = q0 + row;
        float mx = -1e30f;
        for (int c = lane; c < S_LEN; c += 64) {
            int del = min(2, max(-2, c - qglob));
            float s = (sc[row][c] + qrel_s[row][del + 2]) * 0.125f;
            sc[row][c] = s;
            mx = fmaxf(mx, s);
        }
#pragma unroll
        for (int off = 32; off > 0; off >>= 1) mx = fmaxf(mx, __shfl_xor(mx, off));

        float denom = 0.f, suf = 0.f;
        for (int c = lane; c < S_LEN; c += 64) {
            float e = __expf(fminf(sc[row][c] - mx, 0.f));
            sc[row][c] = e;
            denom += e;
            if (c >= qglob + 2) suf += e;
        }
#pragma unroll
        for (int off = 32; off > 0; off >>= 1) {
            denom += __shfl_xor(denom, off);
            suf   += __shfl_xor(suf, off);
        }
        if (lane == 0) {
            float b1  = (qglob >= 1) ? sc[row][qglob - 1] : 0.f;
            float b2v = sc[row][qglob];
            float b3  = (qglob + 1 < S_LEN) ? sc[row][qglob + 1] : 0.f;
            rowstat[row][0] = 1.f / denom;
            rowstat[row][1] = denom - suf - b1 - b2v - b3;
            rowstat[row][2] = b1;
            rowstat[row][3] = b2v;
            rowstat[row][4] = b3;
            rowstat[row][5] = suf;
        }
    }
    __syncthreads();

    // ---- PV: wave w -> (nt = w&3, kc = w>>2) ----
    {
        int nt = wave & 3, kc = wave >> 2;
        f32x4 oacc = zero4();
        const unsigned short* vrow = Vt + v_base + (size_t)(nt * 16 + r) * S_LEN;
        for (int st = 0; st < 16; st++) {
            int kk = kc * 512 + st * 32;
            const f32x4* pv = (const f32x4*)&sc[r][kk + quad * 8];
            f32x4 p0 = pv[0], p1 = pv[1];
            short8 af;
            af[0] = (short)f2b(p0[0]); af[1] = (short)f2b(p0[1]);
            af[2] = (short)f2b(p0[2]); af[3] = (short)f2b(p0[3]);
            af[4] = (short)f2b(p1[0]); af[5] = (short)f2b(p1[1]);
            af[6] = (short)f2b(p1[2]); af[7] = (short)f2b(p1[3]);
            short8 bv = *(const short8*)(vrow + kk + quad * 8);
            oacc = __builtin_amdgcn_mfma_f32_16x16x32_bf16(af, bv, oacc, 0, 0, 0);
        }
#pragma unroll
        for (int i = 0; i < 4; i++)
            pbuf[kc][quad * 4 + i][nt * 16 + r] = oacc[i];
    }
    __syncthreads();

    // ---- epilogue ----
    {
        int orow = tid >> 6, ocol = tid & 63;
        float o = pbuf[0][orow][ocol] + pbuf[1][orow][ocol]
                + pbuf[2][orow][ocol] + pbuf[3][orow][ocol];
        float o2 = rowstat[orow][1] * relv_s[0][ocol]
                 + rowstat[orow][2] * relv_s[1][ocol]
                 + rowstat[orow][3] * relv_s[2][ocol]
                 + rowstat[orow][4] * relv_s[3][ocol]
                 + rowstat[orow][5] * relv_s[4][ocol];
        float res = (o + o2) * rowstat[orow][0];
        Aout[(size_t)(q0 + orow) * DM + col_base + hh * HD + ocol] = f2b(res);
    }
}

// ---------------------------------------------------------------------------
// out[b] = AO @ Wo + bo: A = AO bf16 direct, B = Wo fp32 LDS-staged.
// grid (32, 16), 256 thr.
// ---------------------------------------------------------------------------
__global__ __launch_bounds__(256) void outproj_fused(
    const unsigned short* __restrict__ AO,   // [S][DM] bf16
    const float* __restrict__ Wo,            // [DM][DM] fp32
    const float* __restrict__ bo,
    float* __restrict__ out, int b)
{
    __shared__ unsigned short Bs[64][72];

    int tid = threadIdx.x;
    int wave = tid >> 6, lane = tid & 63;
    int r = lane & 15, quad = lane >> 4;
    int m0 = blockIdx.x * 64 + wave * 16;
    int n0 = blockIdx.y * 64;

    f32x4 acc[4];
#pragma unroll
    for (int nt = 0; nt < 4; nt++) acc[nt] = zero4();

    int kr = tid >> 2;
    int nc = (tid & 3) * 16;
    const short8* ap = (const short8*)(AO + (size_t)(m0 + r) * DM + quad * 8);

    for (int k0 = 0; k0 < DM; k0 += 64) {
        const f32x4* wr = (const f32x4*)(Wo + (size_t)(k0 + kr) * DM + n0 + nc);
        f32x4 w0 = wr[0], w1 = wr[1], w2 = wr[2], w3 = wr[3];
        __syncthreads();
        Bs[nc +  0][kr] = f2b(w0[0]); Bs[nc +  1][kr] = f2b(w0[1]);
        Bs[nc +  2][kr] = f2b(w0[2]); Bs[nc +  3][kr] = f2b(w0[3]);
        Bs[nc +  4][kr] = f2b(w1[0]); Bs[nc +  5][kr] = f2b(w1[1]);
        Bs[nc +  6][kr] = f2b(w1[2]); Bs[nc +  7][kr] = f2b(w1[3]);
        Bs[nc +  8][kr] = f2b(w2[0]); Bs[nc +  9][kr] = f2b(w2[1]);
        Bs[nc + 10][kr] = f2b(w2[2]); Bs[nc + 11][kr] = f2b(w2[3]);
        Bs[nc + 12][kr] = f2b(w3[0]); Bs[nc + 13][kr] = f2b(w3[1]);
        Bs[nc + 14][kr] = f2b(w3[2]); Bs[nc + 15][kr] = f2b(w3[3]);
        __syncthreads();

#pragma unroll
        for (int ks = 0; ks < 2; ks++) {
            short8 a = ap[ks * 4];            // +0 / +32 bf16
#pragma unroll
            for (int nt = 0; nt < 4; nt++) {
                short8 bf = *(const short8*)&Bs[nt * 16 + r][ks * 32 + quad * 8];
                acc[nt] = __builtin_amdgcn_mfma_f32_16x16x32_bf16(a, bf, acc[nt], 0, 0, 0);
            }
        }
        ap += 8;                              // advance 64 bf16
    }

#pragma unroll
    for (int nt = 0; nt < 4; nt++) {
        int n = n0 + nt * 16 + r;
        float bb = bo[n];
#pragma unroll
        for (int i = 0; i < 4; i++) {
            int m = m0 + quad * 4 + i;
            out[((size_t)b * S_LEN + m) * DM + n] = acc[nt][i] + bb;
        }
    }
}

// ---------------------------------------------------------------------------
// Workspace (ushorts): Qs/Ks/Vts [NG*131072] each + AOb [2097152].
//   NG=4  -> 7.34 MB (r8-proven), 18 dispatches.
//   NG=16 -> 16 MB exactly, 6 dispatches (used when ws_size allows).
// ws_size is constant across calls -> branch is graph-safe.
// ---------------------------------------------------------------------------
extern "C" void kernel_launch(void* const* d_in, const int* in_sizes, int n_in,
                              void* d_out, int out_size, void* d_ws, size_t ws_size,
                              hipStream_t stream)
{
    const float* x  = (const float*)d_in[0];
    const float* Wq = (const float*)d_in[1];
    const float* bq = (const float*)d_in[2];
    const float* Wk = (const float*)d_in[3];
    const float* bk = (const float*)d_in[4];
    const float* Wv = (const float*)d_in[5];
    const float* bv = (const float*)d_in[6];
    const float* Wo = (const float*)d_in[7];
    const float* bo = (const float*)d_in[8];
    const float* rk = (const float*)d_in[9];
    const float* rv = (const float*)d_in[10];
    float* outp = (float*)d_out;

    const int NG = (ws_size >= (size_t)16777216) ? 16 : 4;
    const size_t slice = (size_t)NG * S_LEN * HD;   // ushorts per buffer

    unsigned short* ws  = (unsigned short*)d_ws;
    unsigned short* Qs  = ws;
    unsigned short* Ks  = ws + slice;
    unsigned short* Vts = ws + 2 * slice;
    unsigned short* AOb = ws + 3 * slice;           // [S][DM] bf16

    for (int b = 0; b < BATCH; b++) {
        for (int g = 0; g < NH / NG; g++) {
            int head0 = g * NG;
            proj_fused<<<dim3(32, 3 * NG), 256, 0, stream>>>(
                x, Wq, Wk, Wv, bq, bk, bv, Qs, Ks, Vts, b, head0, NG);
            attn_mfma<<<dim3(S_LEN / 16, NG), 1024, 0, stream>>>(
                Qs, Ks, Vts, rk, rv, AOb, head0 * HD);
        }
        outproj_fused<<<dim3(32, 16), 256, 0, stream>>>(AOb, Wo, bo, outp, b);
    }
}

// Round 11
// 617.152 us; speedup vs baseline: 17.8412x; 1.0952x over previous
//
#include <hip/hip_runtime.h>

// Problem: B=2, S=2048, Dm=1024, H=16, D=64, MAX_REL=2. Inputs/out fp32.
// Round 11: attn rewrite — single-pass no-max softmax in registers, bf16 p
// matrix in LDS (66 KB -> 2 blocks/CU), PV reads bf16 fragments directly.
// MFMA conventions HW-verified r7/r8:
//   A[m=lane&15][k=quad*8+j], B[n=lane&15][k=quad*8+j], D[m=quad*4+i][n=lane&15]
// No-max exp is safe: s=(q.k)/8 ~ N(0,1), |s|<~5 -> exp in [7e-3,150], fp32-safe.
#define S_LEN 2048
#define DM    1024
#define NH    16
#define HD    64
#define BATCH 2
#define PPAD  2056   // pmat row stride (ushorts): 2056*2B -> 4-dword bank skew

typedef __attribute__((ext_vector_type(8))) short short8;
typedef __attribute__((ext_vector_type(4))) float f32x4;

__device__ inline float b2f(unsigned short u) {
    return __uint_as_float(((unsigned)u) << 16);
}
__device__ inline unsigned short f2b(float f) {
    unsigned u = __float_as_uint(f);
    u += 0x7FFFu + ((u >> 16) & 1u);   // RNE
    return (unsigned short)(u >> 16);
}
__device__ inline f32x4 zero4() {
    f32x4 z; z[0] = 0.f; z[1] = 0.f; z[2] = 0.f; z[3] = 0.f; return z;
}

// ---------------------------------------------------------------------------
// Fused QKV projection (r10-green, unchanged): A = x fp32 reg-converted,
// B = W fp32 LDS-staged transpose+bf16. grid (32, 3*NG).
// ---------------------------------------------------------------------------
__global__ __launch_bounds__(256) void proj_fused(
    const float* __restrict__ x,
    const float* __restrict__ Wq, const float* __restrict__ Wk,
    const float* __restrict__ Wv,
    const float* __restrict__ bq, const float* __restrict__ bk,
    const float* __restrict__ bv,
    unsigned short* __restrict__ Qs,   // [NG][S][HD] bf16
    unsigned short* __restrict__ Ks,   // [NG][S][HD] bf16
    unsigned short* __restrict__ Vts,  // [NG][HD][S] bf16
    int b, int head0, int NG)
{
    __shared__ unsigned short Bs[64][72];

    int tid = threadIdx.x;
    int wave = tid >> 6, lane = tid & 63;
    int r = lane & 15, quad = lane >> 4;
    int m0 = blockIdx.x * 64 + wave * 16;
    int mat = blockIdx.y / NG;
    int hh  = blockIdx.y % NG;
    int gc0 = (head0 + hh) * 64;

    const float* W    = (mat == 0) ? Wq : (mat == 1) ? Wk : Wv;
    const float* bias = (mat == 0) ? bq : (mat == 1) ? bk : bv;
    const float* xb = x + (size_t)b * S_LEN * DM;

    f32x4 acc[4];
#pragma unroll
    for (int nt = 0; nt < 4; nt++) acc[nt] = zero4();

    int kr = tid >> 2;
    int nc = (tid & 3) * 16;
    const float* am = xb + (size_t)(m0 + r) * DM + quad * 8;

    for (int k0 = 0; k0 < DM; k0 += 64) {
        const f32x4* wr = (const f32x4*)(W + (size_t)(k0 + kr) * DM + gc0 + nc);
        f32x4 w0 = wr[0], w1 = wr[1], w2 = wr[2], w3 = wr[3];
        __syncthreads();
        Bs[nc +  0][kr] = f2b(w0[0]); Bs[nc +  1][kr] = f2b(w0[1]);
        Bs[nc +  2][kr] = f2b(w0[2]); Bs[nc +  3][kr] = f2b(w0[3]);
        Bs[nc +  4][kr] = f2b(w1[0]); Bs[nc +  5][kr] = f2b(w1[1]);
        Bs[nc +  6][kr] = f2b(w1[2]); Bs[nc +  7][kr] = f2b(w1[3]);
        Bs[nc +  8][kr] = f2b(w2[0]); Bs[nc +  9][kr] = f2b(w2[1]);
        Bs[nc + 10][kr] = f2b(w2[2]); Bs[nc + 11][kr] = f2b(w2[3]);
        Bs[nc + 12][kr] = f2b(w3[0]); Bs[nc + 13][kr] = f2b(w3[1]);
        Bs[nc + 14][kr] = f2b(w3[2]); Bs[nc + 15][kr] = f2b(w3[3]);
        __syncthreads();

#pragma unroll
        for (int ks = 0; ks < 2; ks++) {
            const f32x4* ap = (const f32x4*)(am + k0 + ks * 32);
            f32x4 a0 = ap[0], a1 = ap[1];
            short8 a;
            a[0] = (short)f2b(a0[0]); a[1] = (short)f2b(a0[1]);
            a[2] = (short)f2b(a0[2]); a[3] = (short)f2b(a0[3]);
            a[4] = (short)f2b(a1[0]); a[5] = (short)f2b(a1[1]);
            a[6] = (short)f2b(a1[2]); a[7] = (short)f2b(a1[3]);
#pragma unroll
            for (int nt = 0; nt < 4; nt++) {
                short8 bf = *(const short8*)&Bs[nt * 16 + r][ks * 32 + quad * 8];
                acc[nt] = __builtin_amdgcn_mfma_f32_16x16x32_bf16(a, bf, acc[nt], 0, 0, 0);
            }
        }
    }

#pragma unroll
    for (int nt = 0; nt < 4; nt++) {
        int d = nt * 16 + r;
        float bb = bias[gc0 + d];
#pragma unroll
        for (int i = 0; i < 4; i++) {
            int s = m0 + quad * 4 + i;
            float v = acc[nt][i] + bb;
            if (mat == 2)
                Vts[((size_t)hh * HD + d) * S_LEN + s] = f2b(v);
            else if (mat == 0)
                Qs[((size_t)hh * S_LEN + s) * HD + d] = f2b(v);
            else
                Ks[((size_t)hh * S_LEN + s) * HD + d] = f2b(v);
        }
    }
}

// ---------------------------------------------------------------------------
// Fused relative attention v2: 1024 thr = 16 waves, block = (hh, 16 q-rows).
// Phase B: QK^T tile -> +qrel -> *0.125 -> exp (regs) -> bf16 pmat + in-wave
//          denom/suffix partials. Phase C: cross-wave reduce + buckets.
// Phase D: PV MFMA reading bf16 pmat directly. pbuf overlays pmat post-barrier.
// ---------------------------------------------------------------------------
__global__ __launch_bounds__(1024) void attn_mfma(
    const unsigned short* __restrict__ Q,    // [NG][S][HD] bf16
    const unsigned short* __restrict__ Km,   // [NG][S][HD] bf16
    const unsigned short* __restrict__ Vt,   // [NG][HD][S] bf16
    const float* __restrict__ relk,          // [5][64] fp32
    const float* __restrict__ relv,          // [5][64] fp32
    unsigned short* __restrict__ Aout,       // [S][DM] bf16 per-batch
    int col_base)                            // head0*64
{
    __shared__ alignas(16) unsigned short pmat[16][PPAD];  // 65.8 KB bf16 p
    __shared__ float qrel_s[16][5];
    __shared__ float relv_s[5][HD];
    __shared__ float rowstat[16][8];
    __shared__ float wden[16][16];           // [wave][row]
    __shared__ float wsuf[16][16];

    int tid = threadIdx.x;
    int wave = tid >> 6, lane = tid & 63;
    int r = lane & 15, quad = lane >> 4;
    int q0 = blockIdx.x * 16;
    int hh = blockIdx.y;

    size_t qk_base = (size_t)hh * S_LEN * HD;
    size_t v_base  = (size_t)hh * HD * S_LEN;

    // qrel: q-row . rel_k[j] (global reads, L2-hot)
    if (tid < 80) {
        int row = tid / 5, j = tid % 5;
        const unsigned short* qp = Q + qk_base + (size_t)(q0 + row) * HD;
        float s = 0.f;
        for (int d = 0; d < HD; d++) s += b2f(qp[d]) * relk[j * HD + d];
        qrel_s[row][j] = s;
    }
    if (tid < 5 * HD) relv_s[tid >> 6][tid & 63] = relv[tid];

    // A-fragments (verified convention)
    const short8* qp8 = (const short8*)(Q + qk_base + (size_t)(q0 + r) * HD + quad * 8);
    short8 aq0 = qp8[0];
    short8 aq1 = qp8[4];

    __syncthreads();

    // ---- Phase B: QK^T + exp + bf16 store + partial sums ----
    float dpart[4] = {0.f, 0.f, 0.f, 0.f};
    float spart[4] = {0.f, 0.f, 0.f, 0.f};
    int rowq = quad * 4;                      // this lane's row base

    for (int t = 0; t < 8; t++) {
        int col = wave * 128 + t * 16 + r;
        const short8* kp = (const short8*)(Km + qk_base + (size_t)col * HD + quad * 8);
        short8 bk0 = kp[0];
        short8 bk1 = kp[4];
        f32x4 a1 = zero4();
        a1 = __builtin_amdgcn_mfma_f32_16x16x32_bf16(aq0, bk0, a1, 0, 0, 0);
        a1 = __builtin_amdgcn_mfma_f32_16x16x32_bf16(aq1, bk1, a1, 0, 0, 0);
#pragma unroll
        for (int i = 0; i < 4; i++) {
            int row = rowq + i;
            int qglob = q0 + row;
            int del = min(2, max(-2, col - qglob));
            float s = (a1[i] + qrel_s[row][del + 2]) * 0.125f;   // /sqrt(64)
            float e = __expf(s);                                 // no-max: safe
            pmat[row][col] = f2b(e);
            dpart[i] += e;
            if (col >= qglob + 2) spart[i] += e;
        }
    }
    // in-wave reduce across the 16 r-lanes of each quad
#pragma unroll
    for (int off = 1; off <= 8; off <<= 1) {
#pragma unroll
        for (int i = 0; i < 4; i++) {
            dpart[i] += __shfl_xor(dpart[i], off);
            spart[i] += __shfl_xor(spart[i], off);
        }
    }
    if (r == 0) {
#pragma unroll
        for (int i = 0; i < 4; i++) {
            wden[wave][rowq + i] = dpart[i];
            wsuf[wave][rowq + i] = spart[i];
        }
    }
    __syncthreads();

    // ---- Phase C: cross-wave reduce + bucket singles ----
    if (tid < 16) {
        int row = tid, qglob = q0 + row;
        float denom = 0.f, suf = 0.f;
        for (int w = 0; w < 16; w++) { denom += wden[w][row]; suf += wsuf[w][row]; }
        float b1  = (qglob >= 1) ? b2f(pmat[row][qglob - 1]) : 0.f;
        float b2v = b2f(pmat[row][qglob]);
        float b3  = (qglob + 1 < S_LEN) ? b2f(pmat[row][qglob + 1]) : 0.f;
        rowstat[row][0] = 1.f / denom;
        rowstat[row][1] = denom - suf - b1 - b2v - b3;   // bucket 0 (k<=q-2)
        rowstat[row][2] = b1;
        rowstat[row][3] = b2v;
        rowstat[row][4] = b3;
        rowstat[row][5] = suf;                            // bucket 4 (k>=q+2)
    }
    __syncthreads();

    // ---- Phase D: PV, wave -> (nt = w&3, kc = w>>2), bf16 p direct ----
    {
        int nt = wave & 3, kc = wave >> 2;
        f32x4 oacc = zero4();
        const unsigned short* vrow = Vt + v_base + (size_t)(nt * 16 + r) * S_LEN;
        for (int st = 0; st < 16; st++) {
            int kk = kc * 512 + st * 32;
            short8 af = *(const short8*)&pmat[r][kk + quad * 8];
            short8 bv = *(const short8*)(vrow + kk + quad * 8);
            oacc = __builtin_amdgcn_mfma_f32_16x16x32_bf16(af, bv, oacc, 0, 0, 0);
        }
        __syncthreads();                      // ALL pmat reads complete
        float* pbuf = (float*)&pmat[0][0];    // overlay [4][16][65] = 16.6 KB
#pragma unroll
        for (int i = 0; i < 4; i++)
            pbuf[((size_t)kc * 16 + quad * 4 + i) * 65 + nt * 16 + r] = oacc[i];
    }
    __syncthreads();

    // ---- epilogue ----
    {
        const float* pbuf = (const float*)&pmat[0][0];
        int orow = tid >> 6, ocol = tid & 63;
        float o = pbuf[(0 * 16 + orow) * 65 + ocol] + pbuf[(1 * 16 + orow) * 65 + ocol]
                + pbuf[(2 * 16 + orow) * 65 + ocol] + pbuf[(3 * 16 + orow) * 65 + ocol];
        float o2 = rowstat[orow][1] * relv_s[0][ocol]
                 + rowstat[orow][2] * relv_s[1][ocol]
                 + rowstat[orow][3] * relv_s[2][ocol]
                 + rowstat[orow][4] * relv_s[3][ocol]
                 + rowstat[orow][5] * relv_s[4][ocol];
        float res = (o + o2) * rowstat[orow][0];
        Aout[(size_t)(q0 + orow) * DM + col_base + hh * HD + ocol] = f2b(res);
    }
}

// ---------------------------------------------------------------------------
// out[b] = AO @ Wo + bo (r10-green, unchanged). grid (32, 16).
// ---------------------------------------------------------------------------
__global__ __launch_bounds__(256) void outproj_fused(
    const unsigned short* __restrict__ AO,
    const float* __restrict__ Wo,
    const float* __restrict__ bo,
    float* __restrict__ out, int b)
{
    __shared__ unsigned short Bs[64][72];

    int tid = threadIdx.x;
    int wave = tid >> 6, lane = tid & 63;
    int r = lane & 15, quad = lane >> 4;
    int m0 = blockIdx.x * 64 + wave * 16;
    int n0 = blockIdx.y * 64;

    f32x4 acc[4];
#pragma unroll
    for (int nt = 0; nt < 4; nt++) acc[nt] = zero4();

    int kr = tid >> 2;
    int nc = (tid & 3) * 16;
    const short8* ap = (const short8*)(AO + (size_t)(m0 + r) * DM + quad * 8);

    for (int k0 = 0; k0 < DM; k0 += 64) {
        const f32x4* wr = (const f32x4*)(Wo + (size_t)(k0 + kr) * DM + n0 + nc);
        f32x4 w0 = wr[0], w1 = wr[1], w2 = wr[2], w3 = wr[3];
        __syncthreads();
        Bs[nc +  0][kr] = f2b(w0[0]); Bs[nc +  1][kr] = f2b(w0[1]);
        Bs[nc +  2][kr] = f2b(w0[2]); Bs[nc +  3][kr] = f2b(w0[3]);
        Bs[nc +  4][kr] = f2b(w1[0]); Bs[nc +  5][kr] = f2b(w1[1]);
        Bs[nc +  6][kr] = f2b(w1[2]); Bs[nc +  7][kr] = f2b(w1[3]);
        Bs[nc +  8][kr] = f2b(w2[0]); Bs[nc +  9][kr] = f2b(w2[1]);
        Bs[nc + 10][kr] = f2b(w2[2]); Bs[nc + 11][kr] = f2b(w2[3]);
        Bs[nc + 12][kr] = f2b(w3[0]); Bs[nc + 13][kr] = f2b(w3[1]);
        Bs[nc + 14][kr] = f2b(w3[2]); Bs[nc + 15][kr] = f2b(w3[3]);
        __syncthreads();

#pragma unroll
        for (int ks = 0; ks < 2; ks++) {
            short8 a = ap[ks * 4];
#pragma unroll
            for (int nt = 0; nt < 4; nt++) {
                short8 bf = *(const short8*)&Bs[nt * 16 + r][ks * 32 + quad * 8];
                acc[nt] = __builtin_amdgcn_mfma_f32_16x16x32_bf16(a, bf, acc[nt], 0, 0, 0);
            }
        }
        ap += 8;
    }

#pragma unroll
    for (int nt = 0; nt < 4; nt++) {
        int n = n0 + nt * 16 + r;
        float bb = bo[n];
#pragma unroll
        for (int i = 0; i < 4; i++) {
            int m = m0 + quad * 4 + i;
            out[((size_t)b * S_LEN + m) * DM + n] = acc[nt][i] + bb;
        }
    }
}

// ---------------------------------------------------------------------------
// Workspace: NG=16 -> 16 MB (proven r10), 6 dispatches; NG=4 fallback 7.34 MB.
// ---------------------------------------------------------------------------
extern "C" void kernel_launch(void* const* d_in, const int* in_sizes, int n_in,
                              void* d_out, int out_size, void* d_ws, size_t ws_size,
                              hipStream_t stream)
{
    const float* x  = (const float*)d_in[0];
    const float* Wq = (const float*)d_in[1];
    const float* bq = (const float*)d_in[2];
    const float* Wk = (const float*)d_in[3];
    const float* bk = (const float*)d_in[4];
    const float* Wv = (const float*)d_in[5];
    const float* bv = (const float*)d_in[6];
    const float* Wo = (const float*)d_in[7];
    const float* bo = (const float*)d_in[8];
    const float* rk = (const float*)d_in[9];
    const float* rv = (const float*)d_in[10];
    float* outp = (float*)d_out;

    const int NG = (ws_size >= (size_t)16777216) ? 16 : 4;
    const size_t slice = (size_t)NG * S_LEN * HD;

    unsigned short* ws  = (unsigned short*)d_ws;
    unsigned short* Qs  = ws;
    unsigned short* Ks  = ws + slice;
    unsigned short* Vts = ws + 2 * slice;
    unsigned short* AOb = ws + 3 * slice;

    for (int b = 0; b < BATCH; b++) {
        for (int g = 0; g < NH / NG; g++) {
            int head0 = g * NG;
            proj_fused<<<dim3(32, 3 * NG), 256, 0, stream>>>(
                x, Wq, Wk, Wv, bq, bk, bv, Qs, Ks, Vts, b, head0, NG);
            attn_mfma<<<dim3(S_LEN / 16, NG), 1024, 0, stream>>>(
                Qs, Ks, Vts, rk, rv, AOb, head0 * HD);
        }
        outproj_fused<<<dim3(32, 16), 256, 0, stream>>>(AOb, Wo, bo, outp, b);
    }
}